// Round 4
// baseline (2587.977 us; speedup 1.0000x reference)
//
#include <hip/hip_runtime.h>
#include <cstdint>
#include <cstddef>

#define U4    512   // 4*U
#define UNITS 128
#define BATCH 256
#define TSEQ  512
#define FEAT  64
#define SEQS  8                  // sequences per lstm_rec block (fills 16 A-rows)
#define NBLK  (BATCH / SEQS)     // 32 blocks

typedef short short8 __attribute__((ext_vector_type(8)));
typedef float f32x4  __attribute__((ext_vector_type(4)));

// MFMA via inline asm with ALL operands pinned to arch VGPRs.
// Rationale (R3 post-mortem): with the builtin, LLVM allocates B-frags/C in
// AGPRs and emits v_accvgpr_read/write around every MFMA (~300 VALU
// instrs/wave/step, the dominant cost). gfx950 ISA allows A,B,C,D in VGPRs.
#define MFMA_BF16(C, A, B) \
    asm("v_mfma_f32_16x16x32_bf16 %0, %1, %2, %0" : "+v"(C) : "v"(A), "v"(B))

// ---------------- fast activations (fp32, ~1e-7 rel err) ----------------
__device__ __forceinline__ float sigm(float x) {
    float e = __expf(-x);
    return __fdividef(1.0f, 1.0f + e);
}
__device__ __forceinline__ float tanh_fast(float x) {
    float e = __expf(2.0f * x);
    return 1.0f - __fdividef(2.0f, e + 1.0f);
}

// ---------------- bf16 split helpers (RNE) ----------------
__device__ __forceinline__ unsigned short f2bf(float f) {
    unsigned u = __float_as_uint(f);
    unsigned r = u + 0x7FFFu + ((u >> 16) & 1u);
    return (unsigned short)(r >> 16);
}
__device__ __forceinline__ float bf2f(unsigned short h) {
    return __uint_as_float(((unsigned)h) << 16);
}

// ---------------- projection GEMM (unchanged) ----------------
__global__ __launch_bounds__(256, 4)
void proj_gemm(const float* __restrict__ in, const float* __restrict__ W,
               const float* __restrict__ bias, float* __restrict__ out,
               int K, int sB, int sT, int t0, int tcShift)
{
    const int tid = threadIdx.x;
    const int tx = tid & 31;
    const int ty = tid >> 5;
    const int m0 = blockIdx.x * 64;
    const int n0 = blockIdx.y * 128;
    const int TcMask = (1 << tcShift) - 1;

    __shared__ float As[32][68];
    __shared__ float Bs[32][128];

    float4 acc[8];
    #pragma unroll
    for (int i = 0; i < 8; ++i) acc[i] = make_float4(0.f, 0.f, 0.f, 0.f);

    for (int k0 = 0; k0 < K; k0 += 32) {
        #pragma unroll
        for (int i = 0; i < 8; ++i) {
            int l = i * 256 + tid;
            int row = l >> 5, kk = l & 31;
            int rg = m0 + row;
            int b = rg >> tcShift, tc = rg & TcMask;
            As[kk][row] = in[(size_t)b * sB + (size_t)(t0 + tc) * sT + k0 + kk];
        }
        #pragma unroll
        for (int i = 0; i < 4; ++i) {
            int l = i * 256 + tid;
            int kk = l >> 5, jq = l & 31;
            float4 w4 = *(const float4*)(W + (size_t)(k0 + kk) * U4 + n0 + jq * 4);
            *(float4*)(&Bs[kk][jq * 4]) = w4;
        }
        __syncthreads();
        #pragma unroll
        for (int kk = 0; kk < 32; ++kk) {
            float4 b4 = *(const float4*)(&Bs[kk][tx * 4]);
            float4 a0 = *(const float4*)(&As[kk][ty * 8]);
            float4 a1 = *(const float4*)(&As[kk][ty * 8 + 4]);
            float a[8] = {a0.x, a0.y, a0.z, a0.w, a1.x, a1.y, a1.z, a1.w};
            #pragma unroll
            for (int i = 0; i < 8; ++i) {
                acc[i].x = __builtin_fmaf(a[i], b4.x, acc[i].x);
                acc[i].y = __builtin_fmaf(a[i], b4.y, acc[i].y);
                acc[i].z = __builtin_fmaf(a[i], b4.z, acc[i].z);
                acc[i].w = __builtin_fmaf(a[i], b4.w, acc[i].w);
            }
        }
        __syncthreads();
    }

    float4 bb = *(const float4*)(bias + n0 + tx * 4);
    #pragma unroll
    for (int i = 0; i < 8; ++i) {
        int rg = m0 + ty * 8 + i;
        float4 v = acc[i];
        v.x += bb.x; v.y += bb.y; v.z += bb.z; v.w += bb.w;
        *(float4*)(out + (size_t)rg * U4 + n0 + tx * 4) = v;
    }
}

// ---------------- R -> bf16 hi/lo MFMA B-fragments (v5 layout, unchanged) -
// 8 waves/block. Wave w owns units [w*16, w*16+16). Tile g (g=0..3) = gate g
// of those 16 units, lane col m <-> unit w*16+m.
// Frag layout per MFMA (16x16x32 bf16 B): lane holds B[k=kt*32+(lane>>4)*8+j][n=lane&15].
// Rf[layer][w(8)][gate(4)][kt(4)][pass(2)][lane(64)][8 shorts].
__global__ __launch_bounds__(256)
void r_frag(const float* __restrict__ R0, const float* __restrict__ R1,
            const float* __restrict__ R2, unsigned short* __restrict__ out)
{
    int gid = blockIdx.x * 256 + threadIdx.x;    // 3 * 16384
    int l    = gid >> 14;
    int r    = gid & 16383;
    int lane = r & 63;
    int fi   = r >> 6;            // 0..255
    int pass = fi & 1;
    int kt   = (fi >> 1) & 3;
    int gate = (fi >> 3) & 3;
    int w    = fi >> 5;           // 0..7
    const float* R = (l == 0) ? R0 : (l == 1) ? R1 : R2;

    int col = gate * UNITS + w * 16 + (lane & 15);   // original R column
    int k0  = kt * 32 + (lane >> 4) * 8;
    short8 v;
    #pragma unroll
    for (int j = 0; j < 8; ++j) {
        float x = R[(size_t)(k0 + j) * U4 + col];
        unsigned short hi = f2bf(x);
        unsigned short s = pass ? f2bf(x - bf2f(hi)) : hi;
        v[j] = (short)s;
    }
    *(short8*)(out + (size_t)gid * 8) = v;
}

// ---------------- LSTM recurrence via MFMA (v7 = v6 + VGPR-pinned MFMA) --
// 32 blocks x 512 threads (8 waves). Block owns seqs [blk*8, blk*8+8).
// A-rows carry 8 sequences: row 2s = h_hi(seq s), row 2s+1 = h_lo(seq s).
// C-layout (row = 4*quad + reg): lane in quad q holds regs
// {seq 2q hi, seq 2q lo, seq 2q+1 hi, seq 2q+1 lo} -> hi/lo combine is
// IN-LANE; phase B = 2 unit-seq updates per lane, full 64-lane exec, no
// shuffles, ONE barrier/step (double-buffered htab).
// v7 change: MFMA via inline asm, A/B/C/D all "v"-constrained -> B-frags
// (128 regs) live in arch VGPRs, no accvgpr_read/write per MFMA (R3
// post-mortem: those moves were ~450 VALU instr/wave/step = 58% VALUBusy
// on active CUs). s_setprio(1) wraps the MFMA cluster (T5).
__global__ __launch_bounds__(512, 2)
void lstm_rec(const float* __restrict__ xw, const unsigned short* __restrict__ Rf,
              float* __restrict__ h_state, float* __restrict__ c_state,
              float* __restrict__ h_out, int Tc, int init)
{
    const int tid  = threadIdx.x;
    const int blk  = blockIdx.x;
    const int lane = tid & 63;
    const int w    = tid >> 6;       // 0..7, units [w*16, w*16+16)
    const int m    = lane & 15;
    const int quad = lane >> 4;

    // [parity][row 0..15][unit] ; row 2s=hi(seq s), 2s+1=lo(seq s)
    // row stride 136 shorts = 272 B: 16B-aligned; A-read lanes 0-7 (quad 0)
    // span banks {0,4,...,28} -> conflict-free per 8-lane group.
    __shared__ __align__(16) unsigned short htab[2][16][136];

    // B fragments: [gate][kt][pass] = 32 short8 = 128 arch VGPRs (v5 layout)
    short8 bf[4][4][2];
    #pragma unroll
    for (int g = 0; g < 4; ++g)
        #pragma unroll
        for (int kt = 0; kt < 4; ++kt)
            #pragma unroll
            for (int pp = 0; pp < 2; ++pp)
                bf[g][kt][pp] = *(const short8*)(
                    Rf + ((size_t)((((w * 4 + g) * 4 + kt) * 2) + pp) * 64 + lane) * 8);

    const int unit = w * 16 + m;
    const int s0   = 2 * quad;       // lane's first local seq
    const int s1   = s0 + 1;

    float c0 = 0.f, c1 = 0.f;
    if (!init) {
        c0 = c_state[(blk * SEQS + s0) * UNITS + unit];
        c1 = c_state[(blk * SEQS + s1) * UNITS + unit];
    }
    // htab init: thread covers seq (tid>>7) and (tid>>7)+4, unit tid&127
    {
        int uu = tid & 127;
        #pragma unroll
        for (int i = 0; i < 2; ++i) {
            int s = (tid >> 7) + i * 4;
            float hv = init ? 0.f : h_state[(blk * SEQS + s) * UNITS + uu];
            unsigned short hi = f2bf(hv);
            htab[0][2 * s][uu]     = hi;
            htab[0][2 * s + 1][uu] = f2bf(hv - bf2f(hi));
        }
    }
    __syncthreads();

    // per-lane xw bases for its two seqs (gate g at +g*128)
    const float* xw0 = xw + (size_t)(blk * SEQS + s0) * Tc * U4 + unit;
    const float* xw1 = xw + (size_t)(blk * SEQS + s1) * Tc * U4 + unit;

    float xa[8], xb[8];   // xa: even steps, xb: odd steps
    #pragma unroll
    for (int g = 0; g < 4; ++g) {
        xa[g]     = xw0[g * UNITS];
        xa[4 + g] = xw1[g * UNITS];
    }
    {
        const size_t o1 = (size_t)((Tc > 1) ? 1 : 0) * U4;
        #pragma unroll
        for (int g = 0; g < 4; ++g) {
            xb[g]     = xw0[o1 + g * UNITS];
            xb[4 + g] = xw1[o1 + g * UNITS];
        }
    }

    float hl0 = 0.f, hl1 = 0.f;

    auto STEP = [&](int t, int p, float (&xc)[8]) {
        // A-frags: lane reads its row m, k = kt*32 + quad*8 (full wave)
        short8 af[4];
        #pragma unroll
        for (int kt = 0; kt < 4; ++kt)
            af[kt] = *(const short8*)(&htab[p][m][kt * 32 + quad * 8]);

        // C init: xw folded into hi rows (regs 0,2); lo rows 0
        f32x4 C0 = {xc[0], 0.f, xc[4], 0.f};
        f32x4 C1 = {xc[1], 0.f, xc[5], 0.f};
        f32x4 C2 = {xc[2], 0.f, xc[6], 0.f};
        f32x4 C3 = {xc[3], 0.f, xc[7], 0.f};

        // prefetch t+2 into xc (C-init already consumed it)
        int tp = t + 2; if (tp >= Tc) tp = Tc - 1;
        const size_t off = (size_t)tp * U4;
        #pragma unroll
        for (int g = 0; g < 4; ++g) {
            xc[g]     = xw0[off + g * UNITS];
            xc[4 + g] = xw1[off + g * UNITS];
        }

        __builtin_amdgcn_s_setprio(1);
        #pragma unroll
        for (int kt = 0; kt < 4; ++kt) {
            #pragma unroll
            for (int pp = 0; pp < 2; ++pp) {
                MFMA_BF16(C0, af[kt], bf[0][kt][pp]);
                MFMA_BF16(C1, af[kt], bf[1][kt][pp]);
                MFMA_BF16(C2, af[kt], bf[2][kt][pp]);
                MFMA_BF16(C3, af[kt], bf[3][kt][pp]);
            }
        }
        __builtin_amdgcn_s_setprio(0);

        // ---- phase B: in-lane hi+lo combine, 2 unit-seq updates ----
        float zi0 = C0.x + C0.y, zi1 = C0.z + C0.w;
        float zf0 = C1.x + C1.y, zf1 = C1.z + C1.w;
        float zg0 = C2.x + C2.y, zg1 = C2.z + C2.w;
        float zo0 = C3.x + C3.y, zo1 = C3.z + C3.w;

        float iv0 = sigm(zi0), fv0 = sigm(zf0);
        float gv0 = tanh_fast(zg0), ov0 = sigm(zo0);
        c0 = __builtin_fmaf(fv0, c0, iv0 * gv0);
        float hv0 = ov0 * tanh_fast(c0);

        float iv1 = sigm(zi1), fv1 = sigm(zf1);
        float gv1 = tanh_fast(zg1), ov1 = sigm(zo1);
        c1 = __builtin_fmaf(fv1, c1, iv1 * gv1);
        float hv1 = ov1 * tanh_fast(c1);

        hl0 = hv0; hl1 = hv1;

        unsigned short hi0 = f2bf(hv0);
        htab[p ^ 1][4 * quad + 0][unit] = hi0;
        htab[p ^ 1][4 * quad + 1][unit] = f2bf(hv0 - bf2f(hi0));
        unsigned short hi1 = f2bf(hv1);
        htab[p ^ 1][4 * quad + 2][unit] = hi1;
        htab[p ^ 1][4 * quad + 3][unit] = f2bf(hv1 - bf2f(hi1));

        if (h_out) {
            h_out[((size_t)(blk * SEQS + s0) * Tc + t) * UNITS + unit] = hv0;
            h_out[((size_t)(blk * SEQS + s1) * Tc + t) * UNITS + unit] = hv1;
        }
        __syncthreads();   // htab[p^1] ready for next step
    };

    #pragma unroll 1
    for (int t = 0; t < Tc; t += 2) {
        STEP(t,     0, xa);
        STEP(t + 1, 1, xb);
    }

    c_state[(blk * SEQS + s0) * UNITS + unit] = c0;
    c_state[(blk * SEQS + s1) * UNITS + unit] = c1;
    h_state[(blk * SEQS + s0) * UNITS + unit] = hl0;
    h_state[(blk * SEQS + s1) * UNITS + unit] = hl1;
}

// ---------------- dense head ----------------
__global__ __launch_bounds__(256)
void dense_head(const float* __restrict__ h2, const float* __restrict__ Wd,
                const float* __restrict__ bd, float* __restrict__ out)
{
    int b = threadIdx.x;
    float acc[6];
    #pragma unroll
    for (int o = 0; o < 6; ++o) acc[o] = bd[o];
    #pragma unroll 4
    for (int k = 0; k < UNITS; ++k) {
        float hv = h2[b * UNITS + k];
        #pragma unroll
        for (int o = 0; o < 6; ++o)
            acc[o] = __builtin_fmaf(hv, Wd[k * 6 + o], acc[o]);
    }
    #pragma unroll
    for (int o = 0; o < 6; ++o) out[b * 6 + o] = acc[o];
}

extern "C" void kernel_launch(void* const* d_in, const int* in_sizes, int n_in,
                              void* d_out, int out_size, void* d_ws, size_t ws_size,
                              hipStream_t stream)
{
    (void)in_sizes; (void)n_in; (void)out_size;
    const float* x  = (const float*)d_in[0];
    const float* Ws[3] = {(const float*)d_in[1], (const float*)d_in[4], (const float*)d_in[7]};
    const float* Rs[3] = {(const float*)d_in[2], (const float*)d_in[5], (const float*)d_in[8]};
    const float* bs[3] = {(const float*)d_in[3], (const float*)d_in[6], (const float*)d_in[9]};
    const float* Wd = (const float*)d_in[10];
    const float* bd = (const float*)d_in[11];
    float* out = (float*)d_out;

    int tcShift = 7;
    while (tcShift > 2) {
        size_t need = ((size_t)1 << tcShift) * 655360u + 786432u + 786432u;
        if (need <= ws_size) break;
        --tcShift;
    }
    const int Tc = 1 << tcShift;

    float* xw = (float*)d_ws;                                // [B][Tc][512]
    float* hc = xw + (size_t)BATCH * Tc * U4;                // [B][Tc][128]
    float* hs = hc + (size_t)BATCH * Tc * UNITS;             // 3 x [B][128]
    float* cs = hs + 3 * BATCH * UNITS;                      // 3 x [B][128]
    unsigned short* Rf = (unsigned short*)(cs + 3 * BATCH * UNITS); // 3 x 128K shorts

    // precompute v5-permuted bf16 hi/lo MFMA B-fragments of R0..R2
    r_frag<<<192, 256, 0, stream>>>(Rs[0], Rs[1], Rs[2], Rf);

    const int nChunks = TSEQ / Tc;
    for (int ch = 0; ch < nChunks; ++ch) {
        const int t0 = ch * Tc;
        for (int layer = 0; layer < 3; ++layer) {
            const float* in = (layer == 0) ? x : hc;
            const int K  = (layer == 0) ? FEAT : UNITS;
            const int sB = (layer == 0) ? TSEQ * FEAT : Tc * UNITS;
            const int sT = K;
            const int pt0 = (layer == 0) ? t0 : 0;

            dim3 grid(BATCH * Tc / 64, 4);
            proj_gemm<<<grid, 256, 0, stream>>>(in, Ws[layer], bs[layer], xw,
                                                K, sB, sT, pt0, tcShift);

            float* hOut = (layer < 2) ? hc : nullptr;
            lstm_rec<<<NBLK, 512, 0, stream>>>(xw, Rf + (size_t)layer * 131072,
                                               hs + layer * BATCH * UNITS,
                                               cs + layer * BATCH * UNITS,
                                               hOut, Tc, (ch == 0) ? 1 : 0);
        }
    }
    dense_head<<<1, 256, 0, stream>>>(hs + 2 * BATCH * UNITS, Wd, bd, out);
}

// Round 5
// 2570.016 us; speedup vs baseline: 1.0070x; 1.0070x over previous
//
#include <hip/hip_runtime.h>
#include <cstdint>
#include <cstddef>

#define U4    512   // 4*U
#define UNITS 128
#define BATCH 256
#define TSEQ  512
#define FEAT  64
#define SEQS  8                  // sequences per lstm_rec block (fills 16 A-rows)
#define NBLK  (BATCH / SEQS)     // 32 blocks

typedef short short8 __attribute__((ext_vector_type(8)));
typedef float f32x4  __attribute__((ext_vector_type(4)));

// MFMA via inline asm with operands pinned to arch VGPRs (kept from v7;
// perf-neutral but guarantees no accvgpr churn at the asm site).
#define MFMA_BF16(C, A, B) \
    asm("v_mfma_f32_16x16x32_bf16 %0, %1, %2, %0" : "+v"(C) : "v"(A), "v"(B))

// Raw barrier draining ONLY LDS (v8 core change).
// __syncthreads() forces s_waitcnt vmcnt(0) before s_barrier, which
// serializes every step on h_out store completion AND the just-issued xw
// HBM prefetch (~500-900cy) -> the dominant per-step stall (R4 post-mortem:
// v3/v5/v6/v7 all ~2600-3100cy/step regardless of structure).
// Cross-wave data at this barrier is htab (LDS) only -> lgkmcnt(0) suffices.
// sched_barrier(0) fences prevent hoisting across the asm wait (rule #18).
__device__ __forceinline__ void barrier_lds_only() {
    __builtin_amdgcn_sched_barrier(0);
    asm volatile("s_waitcnt lgkmcnt(0)" ::: "memory");
    __builtin_amdgcn_s_barrier();
    __builtin_amdgcn_sched_barrier(0);
}

// ---------------- fast activations (fp32, ~1e-7 rel err) ----------------
__device__ __forceinline__ float sigm(float x) {
    float e = __expf(-x);
    return __fdividef(1.0f, 1.0f + e);
}
__device__ __forceinline__ float tanh_fast(float x) {
    float e = __expf(2.0f * x);
    return 1.0f - __fdividef(2.0f, e + 1.0f);
}

// ---------------- bf16 split helpers (RNE) ----------------
__device__ __forceinline__ unsigned short f2bf(float f) {
    unsigned u = __float_as_uint(f);
    unsigned r = u + 0x7FFFu + ((u >> 16) & 1u);
    return (unsigned short)(r >> 16);
}
__device__ __forceinline__ float bf2f(unsigned short h) {
    return __uint_as_float(((unsigned)h) << 16);
}

// ---------------- projection GEMM (unchanged) ----------------
__global__ __launch_bounds__(256, 4)
void proj_gemm(const float* __restrict__ in, const float* __restrict__ W,
               const float* __restrict__ bias, float* __restrict__ out,
               int K, int sB, int sT, int t0, int tcShift)
{
    const int tid = threadIdx.x;
    const int tx = tid & 31;
    const int ty = tid >> 5;
    const int m0 = blockIdx.x * 64;
    const int n0 = blockIdx.y * 128;
    const int TcMask = (1 << tcShift) - 1;

    __shared__ float As[32][68];
    __shared__ float Bs[32][128];

    float4 acc[8];
    #pragma unroll
    for (int i = 0; i < 8; ++i) acc[i] = make_float4(0.f, 0.f, 0.f, 0.f);

    for (int k0 = 0; k0 < K; k0 += 32) {
        #pragma unroll
        for (int i = 0; i < 8; ++i) {
            int l = i * 256 + tid;
            int row = l >> 5, kk = l & 31;
            int rg = m0 + row;
            int b = rg >> tcShift, tc = rg & TcMask;
            As[kk][row] = in[(size_t)b * sB + (size_t)(t0 + tc) * sT + k0 + kk];
        }
        #pragma unroll
        for (int i = 0; i < 4; ++i) {
            int l = i * 256 + tid;
            int kk = l >> 5, jq = l & 31;
            float4 w4 = *(const float4*)(W + (size_t)(k0 + kk) * U4 + n0 + jq * 4);
            *(float4*)(&Bs[kk][jq * 4]) = w4;
        }
        __syncthreads();
        #pragma unroll
        for (int kk = 0; kk < 32; ++kk) {
            float4 b4 = *(const float4*)(&Bs[kk][tx * 4]);
            float4 a0 = *(const float4*)(&As[kk][ty * 8]);
            float4 a1 = *(const float4*)(&As[kk][ty * 8 + 4]);
            float a[8] = {a0.x, a0.y, a0.z, a0.w, a1.x, a1.y, a1.z, a1.w};
            #pragma unroll
            for (int i = 0; i < 8; ++i) {
                acc[i].x = __builtin_fmaf(a[i], b4.x, acc[i].x);
                acc[i].y = __builtin_fmaf(a[i], b4.y, acc[i].y);
                acc[i].z = __builtin_fmaf(a[i], b4.z, acc[i].z);
                acc[i].w = __builtin_fmaf(a[i], b4.w, acc[i].w);
            }
        }
        __syncthreads();
    }

    float4 bb = *(const float4*)(bias + n0 + tx * 4);
    #pragma unroll
    for (int i = 0; i < 8; ++i) {
        int rg = m0 + ty * 8 + i;
        float4 v = acc[i];
        v.x += bb.x; v.y += bb.y; v.z += bb.z; v.w += bb.w;
        *(float4*)(out + (size_t)rg * U4 + n0 + tx * 4) = v;
    }
}

// ---------------- R -> bf16 hi/lo MFMA B-fragments (v5 layout, unchanged) -
// Rf[layer][w(8)][gate(4)][kt(4)][pass(2)][lane(64)][8 shorts].
__global__ __launch_bounds__(256)
void r_frag(const float* __restrict__ R0, const float* __restrict__ R1,
            const float* __restrict__ R2, unsigned short* __restrict__ out)
{
    int gid = blockIdx.x * 256 + threadIdx.x;    // 3 * 16384
    int l    = gid >> 14;
    int r    = gid & 16383;
    int lane = r & 63;
    int fi   = r >> 6;            // 0..255
    int pass = fi & 1;
    int kt   = (fi >> 1) & 3;
    int gate = (fi >> 3) & 3;
    int w    = fi >> 5;           // 0..7
    const float* R = (l == 0) ? R0 : (l == 1) ? R1 : R2;

    int col = gate * UNITS + w * 16 + (lane & 15);   // original R column
    int k0  = kt * 32 + (lane >> 4) * 8;
    short8 v;
    #pragma unroll
    for (int j = 0; j < 8; ++j) {
        float x = R[(size_t)(k0 + j) * U4 + col];
        unsigned short hi = f2bf(x);
        unsigned short s = pass ? f2bf(x - bf2f(hi)) : hi;
        v[j] = (short)s;
    }
    *(short8*)(out + (size_t)gid * 8) = v;
}

// ---------------- LSTM recurrence via MFMA (v8 = v7 + LDS-only barrier) --
// 32 blocks x 512 threads (8 waves). Block owns seqs [blk*8, blk*8+8).
// A-rows carry 8 sequences: row 2s = h_hi(seq s), row 2s+1 = h_lo(seq s).
// C-layout (row = 4*quad + reg): lane in quad q holds regs
// {seq 2q hi, lo, seq 2q+1 hi, lo} -> hi/lo combine IN-LANE; phase B = 2
// unit-seq updates/lane, full 64-lane exec, ONE lds-only barrier/step
// (double-buffered htab; parity scheme tolerates 1 barrier -- validated v6).
// v8: barrier no longer drains vmcnt -> h_out stores and the 2-step-ahead
// xw prefetch stay in flight across steps; compiler inserts counted
// vmcnt(N) only at the xw USE point.
__global__ __launch_bounds__(512, 2)
void lstm_rec(const float* __restrict__ xw, const unsigned short* __restrict__ Rf,
              float* __restrict__ h_state, float* __restrict__ c_state,
              float* __restrict__ h_out, int Tc, int init)
{
    const int tid  = threadIdx.x;
    const int blk  = blockIdx.x;
    const int lane = tid & 63;
    const int w    = tid >> 6;       // 0..7, units [w*16, w*16+16)
    const int m    = lane & 15;
    const int quad = lane >> 4;

    // [parity][row 0..15][unit] ; row 2s=hi(seq s), 2s+1=lo(seq s)
    __shared__ __align__(16) unsigned short htab[2][16][136];

    // B fragments: [gate][kt][pass] = 32 short8 = 128 regs (v5 layout)
    short8 bf[4][4][2];
    #pragma unroll
    for (int g = 0; g < 4; ++g)
        #pragma unroll
        for (int kt = 0; kt < 4; ++kt)
            #pragma unroll
            for (int pp = 0; pp < 2; ++pp)
                bf[g][kt][pp] = *(const short8*)(
                    Rf + ((size_t)((((w * 4 + g) * 4 + kt) * 2) + pp) * 64 + lane) * 8);

    const int unit = w * 16 + m;
    const int s0   = 2 * quad;       // lane's first local seq
    const int s1   = s0 + 1;

    float c0 = 0.f, c1 = 0.f;
    if (!init) {
        c0 = c_state[(blk * SEQS + s0) * UNITS + unit];
        c1 = c_state[(blk * SEQS + s1) * UNITS + unit];
    }
    // htab init: thread covers seq (tid>>7) and (tid>>7)+4, unit tid&127
    {
        int uu = tid & 127;
        #pragma unroll
        for (int i = 0; i < 2; ++i) {
            int s = (tid >> 7) + i * 4;
            float hv = init ? 0.f : h_state[(blk * SEQS + s) * UNITS + uu];
            unsigned short hi = f2bf(hv);
            htab[0][2 * s][uu]     = hi;
            htab[0][2 * s + 1][uu] = f2bf(hv - bf2f(hi));
        }
    }
    __syncthreads();

    // per-lane xw bases for its two seqs (gate g at +g*128)
    const float* xw0 = xw + (size_t)(blk * SEQS + s0) * Tc * U4 + unit;
    const float* xw1 = xw + (size_t)(blk * SEQS + s1) * Tc * U4 + unit;

    float xa[8], xb[8];   // xa: even steps, xb: odd steps
    #pragma unroll
    for (int g = 0; g < 4; ++g) {
        xa[g]     = xw0[g * UNITS];
        xa[4 + g] = xw1[g * UNITS];
    }
    {
        const size_t o1 = (size_t)((Tc > 1) ? 1 : 0) * U4;
        #pragma unroll
        for (int g = 0; g < 4; ++g) {
            xb[g]     = xw0[o1 + g * UNITS];
            xb[4 + g] = xw1[o1 + g * UNITS];
        }
    }

    float hl0 = 0.f, hl1 = 0.f;

    auto STEP = [&](int t, int p, float (&xc)[8]) {
        // A-frags: lane reads its row m, k = kt*32 + quad*8 (full wave)
        short8 af[4];
        #pragma unroll
        for (int kt = 0; kt < 4; ++kt)
            af[kt] = *(const short8*)(&htab[p][m][kt * 32 + quad * 8]);

        // C init: xw folded into hi rows (regs 0,2); lo rows 0
        f32x4 C0 = {xc[0], 0.f, xc[4], 0.f};
        f32x4 C1 = {xc[1], 0.f, xc[5], 0.f};
        f32x4 C2 = {xc[2], 0.f, xc[6], 0.f};
        f32x4 C3 = {xc[3], 0.f, xc[7], 0.f};

        // prefetch t+2 into xc (C-init already consumed it); stays in
        // flight across the lds-only barrier
        int tp = t + 2; if (tp >= Tc) tp = Tc - 1;
        const size_t off = (size_t)tp * U4;
        #pragma unroll
        for (int g = 0; g < 4; ++g) {
            xc[g]     = xw0[off + g * UNITS];
            xc[4 + g] = xw1[off + g * UNITS];
        }

        __builtin_amdgcn_s_setprio(1);
        #pragma unroll
        for (int kt = 0; kt < 4; ++kt) {
            #pragma unroll
            for (int pp = 0; pp < 2; ++pp) {
                MFMA_BF16(C0, af[kt], bf[0][kt][pp]);
                MFMA_BF16(C1, af[kt], bf[1][kt][pp]);
                MFMA_BF16(C2, af[kt], bf[2][kt][pp]);
                MFMA_BF16(C3, af[kt], bf[3][kt][pp]);
            }
        }
        __builtin_amdgcn_s_setprio(0);

        // ---- phase B: in-lane hi+lo combine, 2 unit-seq updates ----
        float zi0 = C0.x + C0.y, zi1 = C0.z + C0.w;
        float zf0 = C1.x + C1.y, zf1 = C1.z + C1.w;
        float zg0 = C2.x + C2.y, zg1 = C2.z + C2.w;
        float zo0 = C3.x + C3.y, zo1 = C3.z + C3.w;

        float iv0 = sigm(zi0), fv0 = sigm(zf0);
        float gv0 = tanh_fast(zg0), ov0 = sigm(zo0);
        c0 = __builtin_fmaf(fv0, c0, iv0 * gv0);
        float hv0 = ov0 * tanh_fast(c0);

        float iv1 = sigm(zi1), fv1 = sigm(zf1);
        float gv1 = tanh_fast(zg1), ov1 = sigm(zo1);
        c1 = __builtin_fmaf(fv1, c1, iv1 * gv1);
        float hv1 = ov1 * tanh_fast(c1);

        hl0 = hv0; hl1 = hv1;

        unsigned short hi0 = f2bf(hv0);
        htab[p ^ 1][4 * quad + 0][unit] = hi0;
        htab[p ^ 1][4 * quad + 1][unit] = f2bf(hv0 - bf2f(hi0));
        unsigned short hi1 = f2bf(hv1);
        htab[p ^ 1][4 * quad + 2][unit] = hi1;
        htab[p ^ 1][4 * quad + 3][unit] = f2bf(hv1 - bf2f(hi1));

        if (h_out) {
            h_out[((size_t)(blk * SEQS + s0) * Tc + t) * UNITS + unit] = hv0;
            h_out[((size_t)(blk * SEQS + s1) * Tc + t) * UNITS + unit] = hv1;
        }
        barrier_lds_only();   // htab[p^1] visible; vmcnt NOT drained
    };

    #pragma unroll 1
    for (int t = 0; t < Tc; t += 2) {
        STEP(t,     0, xa);
        STEP(t + 1, 1, xb);
    }

    c_state[(blk * SEQS + s0) * UNITS + unit] = c0;
    c_state[(blk * SEQS + s1) * UNITS + unit] = c1;
    h_state[(blk * SEQS + s0) * UNITS + unit] = hl0;
    h_state[(blk * SEQS + s1) * UNITS + unit] = hl1;
}

// ---------------- dense head ----------------
__global__ __launch_bounds__(256)
void dense_head(const float* __restrict__ h2, const float* __restrict__ Wd,
                const float* __restrict__ bd, float* __restrict__ out)
{
    int b = threadIdx.x;
    float acc[6];
    #pragma unroll
    for (int o = 0; o < 6; ++o) acc[o] = bd[o];
    #pragma unroll 4
    for (int k = 0; k < UNITS; ++k) {
        float hv = h2[b * UNITS + k];
        #pragma unroll
        for (int o = 0; o < 6; ++o)
            acc[o] = __builtin_fmaf(hv, Wd[k * 6 + o], acc[o]);
    }
    #pragma unroll
    for (int o = 0; o < 6; ++o) out[b * 6 + o] = acc[o];
}

extern "C" void kernel_launch(void* const* d_in, const int* in_sizes, int n_in,
                              void* d_out, int out_size, void* d_ws, size_t ws_size,
                              hipStream_t stream)
{
    (void)in_sizes; (void)n_in; (void)out_size;
    const float* x  = (const float*)d_in[0];
    const float* Ws[3] = {(const float*)d_in[1], (const float*)d_in[4], (const float*)d_in[7]};
    const float* Rs[3] = {(const float*)d_in[2], (const float*)d_in[5], (const float*)d_in[8]};
    const float* bs[3] = {(const float*)d_in[3], (const float*)d_in[6], (const float*)d_in[9]};
    const float* Wd = (const float*)d_in[10];
    const float* bd = (const float*)d_in[11];
    float* out = (float*)d_out;

    int tcShift = 7;
    while (tcShift > 2) {
        size_t need = ((size_t)1 << tcShift) * 655360u + 786432u + 786432u;
        if (need <= ws_size) break;
        --tcShift;
    }
    const int Tc = 1 << tcShift;

    float* xw = (float*)d_ws;                                // [B][Tc][512]
    float* hc = xw + (size_t)BATCH * Tc * U4;                // [B][Tc][128]
    float* hs = hc + (size_t)BATCH * Tc * UNITS;             // 3 x [B][128]
    float* cs = hs + 3 * BATCH * UNITS;                      // 3 x [B][128]
    unsigned short* Rf = (unsigned short*)(cs + 3 * BATCH * UNITS); // 3 x 128K shorts

    // precompute v5-permuted bf16 hi/lo MFMA B-fragments of R0..R2
    r_frag<<<192, 256, 0, stream>>>(Rs[0], Rs[1], Rs[2], Rf);

    const int nChunks = TSEQ / Tc;
    for (int ch = 0; ch < nChunks; ++ch) {
        const int t0 = ch * Tc;
        for (int layer = 0; layer < 3; ++layer) {
            const float* in = (layer == 0) ? x : hc;
            const int K  = (layer == 0) ? FEAT : UNITS;
            const int sB = (layer == 0) ? TSEQ * FEAT : Tc * UNITS;
            const int sT = K;
            const int pt0 = (layer == 0) ? t0 : 0;

            dim3 grid(BATCH * Tc / 64, 4);
            proj_gemm<<<grid, 256, 0, stream>>>(in, Ws[layer], bs[layer], xw,
                                                K, sB, sT, pt0, tcShift);

            float* hOut = (layer < 2) ? hc : nullptr;
            lstm_rec<<<NBLK, 512, 0, stream>>>(xw, Rf + (size_t)layer * 131072,
                                               hs + layer * BATCH * UNITS,
                                               cs + layer * BATCH * UNITS,
                                               hOut, Tc, (ch == 0) ? 1 : 0);
        }
    }
    dense_head<<<1, 256, 0, stream>>>(hs + 2 * BATCH * UNITS, Wd, bd, out);
}

// Round 6
// 1620.729 us; speedup vs baseline: 1.5968x; 1.5857x over previous
//
#include <hip/hip_runtime.h>
#include <cstdint>
#include <cstddef>

#define U4    512   // 4*U
#define UNITS 128
#define BATCH 256
#define TSEQ  512
#define FEAT  64
#define SEQS  8                  // sequences per lstm_rec block (fills 16 A-rows)
#define NBLK  (BATCH / SEQS)     // 32 blocks per cell

typedef short short8 __attribute__((ext_vector_type(8)));
typedef float f32x4  __attribute__((ext_vector_type(4)));

// MFMA via inline asm with operands pinned to arch VGPRs (v7; perf-neutral
// but guarantees no accvgpr churn at the asm site).
#define MFMA_BF16(C, A, B) \
    asm("v_mfma_f32_16x16x32_bf16 %0, %1, %2, %0" : "+v"(C) : "v"(A), "v"(B))

// Raw barrier draining ONLY LDS (v8; neutral vs __syncthreads but keeps
// h_out stores / xw prefetch in flight across steps).
__device__ __forceinline__ void barrier_lds_only() {
    __builtin_amdgcn_sched_barrier(0);
    asm volatile("s_waitcnt lgkmcnt(0)" ::: "memory");
    __builtin_amdgcn_s_barrier();
    __builtin_amdgcn_sched_barrier(0);
}

// ---------------- fast activations (fp32, ~1e-7 rel err) ----------------
__device__ __forceinline__ float sigm(float x) {
    float e = __expf(-x);
    return __fdividef(1.0f, 1.0f + e);
}
__device__ __forceinline__ float tanh_fast(float x) {
    float e = __expf(2.0f * x);
    return 1.0f - __fdividef(2.0f, e + 1.0f);
}

// ---------------- bf16 split helpers (RNE) ----------------
__device__ __forceinline__ unsigned short f2bf(float f) {
    unsigned u = __float_as_uint(f);
    unsigned r = u + 0x7FFFu + ((u >> 16) & 1u);
    return (unsigned short)(r >> 16);
}
__device__ __forceinline__ float bf2f(unsigned short h) {
    return __uint_as_float(((unsigned)h) << 16);
}

// ---------------- projection GEMM (unchanged) ----------------
__global__ __launch_bounds__(256, 4)
void proj_gemm(const float* __restrict__ in, const float* __restrict__ W,
               const float* __restrict__ bias, float* __restrict__ out,
               int K, int sB, int sT, int t0, int tcShift)
{
    const int tid = threadIdx.x;
    const int tx = tid & 31;
    const int ty = tid >> 5;
    const int m0 = blockIdx.x * 64;
    const int n0 = blockIdx.y * 128;
    const int TcMask = (1 << tcShift) - 1;

    __shared__ float As[32][68];
    __shared__ float Bs[32][128];

    float4 acc[8];
    #pragma unroll
    for (int i = 0; i < 8; ++i) acc[i] = make_float4(0.f, 0.f, 0.f, 0.f);

    for (int k0 = 0; k0 < K; k0 += 32) {
        #pragma unroll
        for (int i = 0; i < 8; ++i) {
            int l = i * 256 + tid;
            int row = l >> 5, kk = l & 31;
            int rg = m0 + row;
            int b = rg >> tcShift, tc = rg & TcMask;
            As[kk][row] = in[(size_t)b * sB + (size_t)(t0 + tc) * sT + k0 + kk];
        }
        #pragma unroll
        for (int i = 0; i < 4; ++i) {
            int l = i * 256 + tid;
            int kk = l >> 5, jq = l & 31;
            float4 w4 = *(const float4*)(W + (size_t)(k0 + kk) * U4 + n0 + jq * 4);
            *(float4*)(&Bs[kk][jq * 4]) = w4;
        }
        __syncthreads();
        #pragma unroll
        for (int kk = 0; kk < 32; ++kk) {
            float4 b4 = *(const float4*)(&Bs[kk][tx * 4]);
            float4 a0 = *(const float4*)(&As[kk][ty * 8]);
            float4 a1 = *(const float4*)(&As[kk][ty * 8 + 4]);
            float a[8] = {a0.x, a0.y, a0.z, a0.w, a1.x, a1.y, a1.z, a1.w};
            #pragma unroll
            for (int i = 0; i < 8; ++i) {
                acc[i].x = __builtin_fmaf(a[i], b4.x, acc[i].x);
                acc[i].y = __builtin_fmaf(a[i], b4.y, acc[i].y);
                acc[i].z = __builtin_fmaf(a[i], b4.z, acc[i].z);
                acc[i].w = __builtin_fmaf(a[i], b4.w, acc[i].w);
            }
        }
        __syncthreads();
    }

    float4 bb = *(const float4*)(bias + n0 + tx * 4);
    #pragma unroll
    for (int i = 0; i < 8; ++i) {
        int rg = m0 + ty * 8 + i;
        float4 v = acc[i];
        v.x += bb.x; v.y += bb.y; v.z += bb.z; v.w += bb.w;
        *(float4*)(out + (size_t)rg * U4 + n0 + tx * 4) = v;
    }
}

// ---------------- R -> bf16 hi/lo MFMA B-fragments (v5 layout, unchanged) -
// Rf[layer][w(8)][gate(4)][kt(4)][pass(2)][lane(64)][8 shorts].
__global__ __launch_bounds__(256)
void r_frag(const float* __restrict__ R0, const float* __restrict__ R1,
            const float* __restrict__ R2, unsigned short* __restrict__ out)
{
    int gid = blockIdx.x * 256 + threadIdx.x;    // 3 * 16384
    int l    = gid >> 14;
    int r    = gid & 16383;
    int lane = r & 63;
    int fi   = r >> 6;            // 0..255
    int pass = fi & 1;
    int kt   = (fi >> 1) & 3;
    int gate = (fi >> 3) & 3;
    int w    = fi >> 5;           // 0..7
    const float* R = (l == 0) ? R0 : (l == 1) ? R1 : R2;

    int col = gate * UNITS + w * 16 + (lane & 15);   // original R column
    int k0  = kt * 32 + (lane >> 4) * 8;
    short8 v;
    #pragma unroll
    for (int j = 0; j < 8; ++j) {
        float x = R[(size_t)(k0 + j) * U4 + col];
        unsigned short hi = f2bf(x);
        unsigned short s = pass ? f2bf(x - bf2f(hi)) : hi;
        v[j] = (short)s;
    }
    *(short8*)(out + (size_t)gid * 8) = v;
}

// ---------------- wavefront-batched LSTM recurrence (v9) -----------------
// Cell internals identical to v8 (validated, absmax 1.5e-5). v9 batches the
// independent anti-diagonal cells (ch,layer) of the chunk x layer pipeline
// into ONE launch: grid = (32 blocks/cell, ncells<=3). R5 post-mortem:
// active CUs are ~90% pipe-busy but only 32/256 CUs work per cell ->
// between-cell parallelism is the only lever left; 12 serialized cell
// launches become 6 stages of 1-3 concurrent cells.
struct Cell {
    const float* xw;
    const unsigned short* rf;
    float* hs;
    float* cs;
    float* hout;
    int init;
    int pad_;
};
struct StageArgs { Cell c[3]; };

__global__ __launch_bounds__(512, 2)
void lstm_rec(StageArgs sa, int Tc)
{
    const Cell ce = sa.c[blockIdx.y];
    const float* __restrict__ xw = ce.xw;
    const unsigned short* __restrict__ Rf = ce.rf;
    float* __restrict__ h_state = ce.hs;
    float* __restrict__ c_state = ce.cs;
    float* __restrict__ h_out = ce.hout;
    const int init = ce.init;

    const int tid  = threadIdx.x;
    const int blk  = blockIdx.x;
    const int lane = tid & 63;
    const int w    = tid >> 6;       // 0..7, units [w*16, w*16+16)
    const int m    = lane & 15;
    const int quad = lane >> 4;

    // [parity][row 0..15][unit] ; row 2s=hi(seq s), 2s+1=lo(seq s)
    __shared__ __align__(16) unsigned short htab[2][16][136];

    // B fragments: [gate][kt][pass] = 32 short8 = 128 regs (v5 layout)
    short8 bf[4][4][2];
    #pragma unroll
    for (int g = 0; g < 4; ++g)
        #pragma unroll
        for (int kt = 0; kt < 4; ++kt)
            #pragma unroll
            for (int pp = 0; pp < 2; ++pp)
                bf[g][kt][pp] = *(const short8*)(
                    Rf + ((size_t)((((w * 4 + g) * 4 + kt) * 2) + pp) * 64 + lane) * 8);

    const int unit = w * 16 + m;
    const int s0   = 2 * quad;       // lane's first local seq
    const int s1   = s0 + 1;

    float c0 = 0.f, c1 = 0.f;
    if (!init) {
        c0 = c_state[(blk * SEQS + s0) * UNITS + unit];
        c1 = c_state[(blk * SEQS + s1) * UNITS + unit];
    }
    // htab init: thread covers seq (tid>>7) and (tid>>7)+4, unit tid&127
    {
        int uu = tid & 127;
        #pragma unroll
        for (int i = 0; i < 2; ++i) {
            int s = (tid >> 7) + i * 4;
            float hv = init ? 0.f : h_state[(blk * SEQS + s) * UNITS + uu];
            unsigned short hi = f2bf(hv);
            htab[0][2 * s][uu]     = hi;
            htab[0][2 * s + 1][uu] = f2bf(hv - bf2f(hi));
        }
    }
    __syncthreads();

    // per-lane xw bases for its two seqs (gate g at +g*128)
    const float* xw0 = xw + (size_t)(blk * SEQS + s0) * Tc * U4 + unit;
    const float* xw1 = xw + (size_t)(blk * SEQS + s1) * Tc * U4 + unit;

    float xa[8], xb[8];   // xa: even steps, xb: odd steps
    #pragma unroll
    for (int g = 0; g < 4; ++g) {
        xa[g]     = xw0[g * UNITS];
        xa[4 + g] = xw1[g * UNITS];
    }
    {
        const size_t o1 = (size_t)((Tc > 1) ? 1 : 0) * U4;
        #pragma unroll
        for (int g = 0; g < 4; ++g) {
            xb[g]     = xw0[o1 + g * UNITS];
            xb[4 + g] = xw1[o1 + g * UNITS];
        }
    }

    float hl0 = 0.f, hl1 = 0.f;

    auto STEP = [&](int t, int p, float (&xc)[8]) {
        // A-frags: lane reads its row m, k = kt*32 + quad*8 (full wave)
        short8 af[4];
        #pragma unroll
        for (int kt = 0; kt < 4; ++kt)
            af[kt] = *(const short8*)(&htab[p][m][kt * 32 + quad * 8]);

        // C init: xw folded into hi rows (regs 0,2); lo rows 0
        f32x4 C0 = {xc[0], 0.f, xc[4], 0.f};
        f32x4 C1 = {xc[1], 0.f, xc[5], 0.f};
        f32x4 C2 = {xc[2], 0.f, xc[6], 0.f};
        f32x4 C3 = {xc[3], 0.f, xc[7], 0.f};

        // prefetch t+2 into xc; stays in flight across the lds-only barrier
        int tp = t + 2; if (tp >= Tc) tp = Tc - 1;
        const size_t off = (size_t)tp * U4;
        #pragma unroll
        for (int g = 0; g < 4; ++g) {
            xc[g]     = xw0[off + g * UNITS];
            xc[4 + g] = xw1[off + g * UNITS];
        }

        __builtin_amdgcn_s_setprio(1);
        #pragma unroll
        for (int kt = 0; kt < 4; ++kt) {
            #pragma unroll
            for (int pp = 0; pp < 2; ++pp) {
                MFMA_BF16(C0, af[kt], bf[0][kt][pp]);
                MFMA_BF16(C1, af[kt], bf[1][kt][pp]);
                MFMA_BF16(C2, af[kt], bf[2][kt][pp]);
                MFMA_BF16(C3, af[kt], bf[3][kt][pp]);
            }
        }
        __builtin_amdgcn_s_setprio(0);

        // ---- phase B: in-lane hi+lo combine, 2 unit-seq updates ----
        float zi0 = C0.x + C0.y, zi1 = C0.z + C0.w;
        float zf0 = C1.x + C1.y, zf1 = C1.z + C1.w;
        float zg0 = C2.x + C2.y, zg1 = C2.z + C2.w;
        float zo0 = C3.x + C3.y, zo1 = C3.z + C3.w;

        float iv0 = sigm(zi0), fv0 = sigm(zf0);
        float gv0 = tanh_fast(zg0), ov0 = sigm(zo0);
        c0 = __builtin_fmaf(fv0, c0, iv0 * gv0);
        float hv0 = ov0 * tanh_fast(c0);

        float iv1 = sigm(zi1), fv1 = sigm(zf1);
        float gv1 = tanh_fast(zg1), ov1 = sigm(zo1);
        c1 = __builtin_fmaf(fv1, c1, iv1 * gv1);
        float hv1 = ov1 * tanh_fast(c1);

        hl0 = hv0; hl1 = hv1;

        unsigned short hi0 = f2bf(hv0);
        htab[p ^ 1][4 * quad + 0][unit] = hi0;
        htab[p ^ 1][4 * quad + 1][unit] = f2bf(hv0 - bf2f(hi0));
        unsigned short hi1 = f2bf(hv1);
        htab[p ^ 1][4 * quad + 2][unit] = hi1;
        htab[p ^ 1][4 * quad + 3][unit] = f2bf(hv1 - bf2f(hi1));

        if (h_out) {
            h_out[((size_t)(blk * SEQS + s0) * Tc + t) * UNITS + unit] = hv0;
            h_out[((size_t)(blk * SEQS + s1) * Tc + t) * UNITS + unit] = hv1;
        }
        barrier_lds_only();   // htab[p^1] visible; vmcnt NOT drained
    };

    #pragma unroll 1
    for (int t = 0; t < Tc; t += 2) {
        STEP(t,     0, xa);
        STEP(t + 1, 1, xb);
    }

    c_state[(blk * SEQS + s0) * UNITS + unit] = c0;
    c_state[(blk * SEQS + s1) * UNITS + unit] = c1;
    h_state[(blk * SEQS + s0) * UNITS + unit] = hl0;
    h_state[(blk * SEQS + s1) * UNITS + unit] = hl1;
}

// ---------------- dense head ----------------
__global__ __launch_bounds__(256)
void dense_head(const float* __restrict__ h2, const float* __restrict__ Wd,
                const float* __restrict__ bd, float* __restrict__ out)
{
    int b = threadIdx.x;
    float acc[6];
    #pragma unroll
    for (int o = 0; o < 6; ++o) acc[o] = bd[o];
    #pragma unroll 4
    for (int k = 0; k < UNITS; ++k) {
        float hv = h2[b * UNITS + k];
        #pragma unroll
        for (int o = 0; o < 6; ++o)
            acc[o] = __builtin_fmaf(hv, Wd[k * 6 + o], acc[o]);
    }
    #pragma unroll
    for (int o = 0; o < 6; ++o) out[b * 6 + o] = acc[o];
}

extern "C" void kernel_launch(void* const* d_in, const int* in_sizes, int n_in,
                              void* d_out, int out_size, void* d_ws, size_t ws_size,
                              hipStream_t stream)
{
    (void)in_sizes; (void)n_in; (void)out_size;
    const float* x  = (const float*)d_in[0];
    const float* Ws[3] = {(const float*)d_in[1], (const float*)d_in[4], (const float*)d_in[7]};
    const float* Rs[3] = {(const float*)d_in[2], (const float*)d_in[5], (const float*)d_in[8]};
    const float* bs[3] = {(const float*)d_in[3], (const float*)d_in[6], (const float*)d_in[9]};
    const float* Wd = (const float*)d_in[10];
    const float* bd = (const float*)d_in[11];
    float* out = (float*)d_out;

    // ws need: 3x xw (per-layer) + 2x hc (per-layer) + hs/cs + Rf
    //   = Tc*1,835,008 + 1,572,864 bytes
    int tcShift = 7;
    while (tcShift > 2) {
        size_t need = ((size_t)1 << tcShift) * 1835008u + 1572864u;
        if (need <= ws_size) break;
        --tcShift;
    }
    const int Tc = 1 << tcShift;
    const int nCh = TSEQ / Tc;

    float* xw3 = (float*)d_ws;                                   // 3 x [B][Tc][512]
    float* hc2 = xw3 + 3 * (size_t)BATCH * Tc * U4;              // 2 x [B][Tc][128]
    float* hs  = hc2 + 2 * (size_t)BATCH * Tc * UNITS;           // 3 x [B][128]
    float* cs  = hs + 3 * BATCH * UNITS;                         // 3 x [B][128]
    unsigned short* Rf = (unsigned short*)(cs + 3 * BATCH * UNITS); // 3 x 128K shorts

    const size_t xwStride = (size_t)BATCH * Tc * U4;
    const size_t hcStride = (size_t)BATCH * Tc * UNITS;

    // precompute v5-permuted bf16 hi/lo MFMA B-fragments of R0..R2
    r_frag<<<192, 256, 0, stream>>>(Rs[0], Rs[1], Rs[2], Rf);

    // anti-diagonal wavefront over (chunk c, layer lam), c+lam = s.
    // Within a stage: all projs first (consume hc written last stage),
    // then ONE batched lstm launch (cells are independent: distinct layers
    // -> distinct xw/hc/hs/cs buffers).
    for (int s = 0; s <= nCh + 1; ++s) {
        int lo = s - (nCh - 1); if (lo < 0) lo = 0;
        int hi = (s < 2) ? s : 2;
        if (lo > hi) continue;

        for (int lam = lo; lam <= hi; ++lam) {
            int c = s - lam;
            const float* in = (lam == 0) ? x : hc2 + (size_t)(lam - 1) * hcStride;
            const int K  = (lam == 0) ? FEAT : UNITS;
            const int sB = (lam == 0) ? TSEQ * FEAT : Tc * UNITS;
            const int sT = K;
            const int pt0 = (lam == 0) ? c * Tc : 0;
            dim3 grid(BATCH * Tc / 64, 4);
            proj_gemm<<<grid, 256, 0, stream>>>(in, Ws[lam], bs[lam],
                                                xw3 + (size_t)lam * xwStride,
                                                K, sB, sT, pt0, tcShift);
        }

        StageArgs sa{};
        int n = 0;
        for (int lam = lo; lam <= hi; ++lam) {
            int c = s - lam;
            sa.c[n].xw   = xw3 + (size_t)lam * xwStride;
            sa.c[n].rf   = Rf + (size_t)lam * 131072;
            sa.c[n].hs   = hs + lam * BATCH * UNITS;
            sa.c[n].cs   = cs + lam * BATCH * UNITS;
            sa.c[n].hout = (lam < 2) ? (hc2 + (size_t)lam * hcStride) : nullptr;
            sa.c[n].init = (c == 0) ? 1 : 0;
            ++n;
        }
        lstm_rec<<<dim3(NBLK, n), 512, 0, stream>>>(sa, Tc);
    }

    dense_head<<<1, 256, 0, stream>>>(hs + 2 * BATCH * UNITS, Wd, bd, out);
}

// Round 7
// 1465.077 us; speedup vs baseline: 1.7664x; 1.1062x over previous
//
#include <hip/hip_runtime.h>
#include <cstdint>
#include <cstddef>

#define U4    512   // 4*U
#define UNITS 128
#define BATCH 256
#define TSEQ  512
#define FEAT  64
#define SEQS  8                  // sequences per lstm_rec block (fills 16 A-rows)
#define NBLK  (BATCH / SEQS)     // 32 blocks per cell

typedef short short8 __attribute__((ext_vector_type(8)));
typedef float f32x4  __attribute__((ext_vector_type(4)));

// MFMA via inline asm with operands pinned to arch VGPRs (lstm path, v7).
#define MFMA_BF16(C, A, B) \
    asm("v_mfma_f32_16x16x32_bf16 %0, %1, %2, %0" : "+v"(C) : "v"(A), "v"(B))

// Raw barrier draining ONLY LDS (v8).
__device__ __forceinline__ void barrier_lds_only() {
    __builtin_amdgcn_sched_barrier(0);
    asm volatile("s_waitcnt lgkmcnt(0)" ::: "memory");
    __builtin_amdgcn_s_barrier();
    __builtin_amdgcn_sched_barrier(0);
}

// ---------------- fast activations (fp32, ~1e-7 rel err) ----------------
__device__ __forceinline__ float sigm(float x) {
    float e = __expf(-x);
    return __fdividef(1.0f, 1.0f + e);
}
__device__ __forceinline__ float tanh_fast(float x) {
    float e = __expf(2.0f * x);
    return 1.0f - __fdividef(2.0f, e + 1.0f);
}

// ---------------- bf16 split helpers (RNE) ----------------
__device__ __forceinline__ unsigned short f2bf(float f) {
    unsigned u = __float_as_uint(f);
    unsigned r = u + 0x7FFFu + ((u >> 16) & 1u);
    return (unsigned short)(r >> 16);
}
__device__ __forceinline__ float bf2f(unsigned short h) {
    return __uint_as_float(((unsigned)h) << 16);
}

// ---------------- R -> bf16 hi/lo MFMA B-fragments (v5 layout, unchanged) -
// Rf[layer][w(8)][gate(4)][kt(4)][pass(2)][lane(64)][8 shorts].
__global__ __launch_bounds__(256)
void r_frag(const float* __restrict__ R0, const float* __restrict__ R1,
            const float* __restrict__ R2, unsigned short* __restrict__ out)
{
    int gid = blockIdx.x * 256 + threadIdx.x;    // 3 * 16384
    int l    = gid >> 14;
    int r    = gid & 16383;
    int lane = r & 63;
    int fi   = r >> 6;            // 0..255
    int pass = fi & 1;
    int kt   = (fi >> 1) & 3;
    int gate = (fi >> 3) & 3;
    int w    = fi >> 5;           // 0..7
    const float* R = (l == 0) ? R0 : (l == 1) ? R1 : R2;

    int col = gate * UNITS + w * 16 + (lane & 15);   // original R column
    int k0  = kt * 32 + (lane >> 4) * 8;
    short8 v;
    #pragma unroll
    for (int j = 0; j < 8; ++j) {
        float x = R[(size_t)(k0 + j) * U4 + col];
        unsigned short hi = f2bf(x);
        unsigned short s = pass ? f2bf(x - bf2f(hi)) : hi;
        v[j] = (short)s;
    }
    *(short8*)(out + (size_t)gid * 8) = v;
}

// ---------------- W -> bf16 hi/lo MFMA B-fragments (v10, r_frag mirror) ---
// Wf[layer][nt(32)][kt(4)][pass(2)][lane(64)][8 shorts]. No column permute
// (xw consumed in original gate-major order). Layer 0 has K=64: kt>=2 -> 0.
__global__ __launch_bounds__(256)
void w_frag(const float* __restrict__ W0, const float* __restrict__ W1,
            const float* __restrict__ W2, unsigned short* __restrict__ out)
{
    int gid = blockIdx.x * 256 + threadIdx.x;    // 3 * 16384
    int l    = gid >> 14;
    int r    = gid & 16383;
    int lane = r & 63;
    int fi   = r >> 6;            // 0..255
    int pass = fi & 1;
    int kt   = (fi >> 1) & 3;
    int nt   = fi >> 3;           // 0..31
    const float* W = (l == 0) ? W0 : (l == 1) ? W1 : W2;
    const int K = (l == 0) ? FEAT : UNITS;

    int col = nt * 16 + (lane & 15);
    int k0  = kt * 32 + (lane >> 4) * 8;
    short8 v;
    #pragma unroll
    for (int j = 0; j < 8; ++j) {
        float x = (k0 + j < K) ? W[(size_t)(k0 + j) * U4 + col] : 0.f;
        unsigned short hi = f2bf(x);
        unsigned short s = pass ? f2bf(x - bf2f(hi)) : hi;
        v[j] = (short)s;
    }
    *(short8*)(out + (size_t)gid * 8) = v;
}

// ---------------- projection GEMM via MFMA (v10) -------------------------
// Replaces the fp32 VALU proj (43 GFLOP @157TF ceiling, ~420us measured).
// Reuses the lstm's validated bf16 hi/lo layout: A-tile = 8 time-rows x
// {hi,lo} interleaved (16 A-rows); B = Wf hi/lo passes. All 4 products
// accumulate in fp32 -> xw at ~fp32 accuracy. In-lane hi/lo combine
// (z = C[0]+C[1] / C[2]+C[3], same as lstm phase B). Bias in epilogue.
// Block: 512 thr (8 waves); wave w owns cols [w*64, w*64+64); block owns
// 64 time-rows; batched over <=3 stage cells via blockIdx.y.
struct PCell {
    const float* in;
    float* out;
    const unsigned short* wf;
    const float* bias;
    int sB, sT, t0, K;
};
struct PStage { PCell c[3]; };

__global__ __launch_bounds__(512, 2)
void proj_mfma(PStage ps, int tcShift)
{
    const PCell ce = ps.c[blockIdx.y];
    const int tid  = threadIdx.x;
    const int lane = tid & 63;
    const int w    = tid >> 6;       // 0..7
    const int m    = lane & 15;
    const int quad = lane >> 4;
    const int TcMask = (1 << tcShift) - 1;
    const int m0 = blockIdx.x * 64;

    // [rowgroup 0..7][16 rows: 2*(t&7)=hi, +1=lo][k], stride 136 like htab
    __shared__ __align__(16) unsigned short atab[8][16][136];

    // B fragments: [nt 0..3][kt 0..3][pass] = 32 short8 = 128 regs
    short8 bf[4][4][2];
    #pragma unroll
    for (int nt = 0; nt < 4; ++nt)
        #pragma unroll
        for (int kt = 0; kt < 4; ++kt)
            #pragma unroll
            for (int pp = 0; pp < 2; ++pp)
                bf[nt][kt][pp] = *(const short8*)(
                    ce.wf + ((size_t)((((w * 4 + nt) * 4 + kt) * 2) + pp) * 64 + lane) * 8);

    // stage 64 rows x 128 k (zeros for k >= K), split hi/lo
    const float* __restrict__ inp = ce.in;
    #pragma unroll
    for (int rep = 0; rep < 16; ++rep) {
        int idx = rep * 512 + tid;
        int row = idx >> 7;          // 0..63
        int k   = idx & 127;
        int rg  = m0 + row;
        int b = rg >> tcShift, tc = rg & TcMask;
        float x = 0.f;
        if (k < ce.K)
            x = inp[(size_t)b * ce.sB + (size_t)(ce.t0 + tc) * ce.sT + k];
        unsigned short hi = f2bf(x);
        atab[row >> 3][2 * (row & 7)][k]     = hi;
        atab[row >> 3][2 * (row & 7) + 1][k] = f2bf(x - bf2f(hi));
    }
    __syncthreads();

    float bb[4];
    #pragma unroll
    for (int nt = 0; nt < 4; ++nt) bb[nt] = ce.bias[w * 64 + nt * 16 + m];

    float* __restrict__ outp = ce.out;
    #pragma unroll 1
    for (int r = 0; r < 8; ++r) {
        short8 af[4];
        #pragma unroll
        for (int kt = 0; kt < 4; ++kt)
            af[kt] = *(const short8*)(&atab[r][m][kt * 32 + quad * 8]);

        f32x4 C[4];
        #pragma unroll
        for (int nt = 0; nt < 4; ++nt) C[nt] = f32x4{0.f, 0.f, 0.f, 0.f};

        // 4 independent chains of depth 8
        #pragma unroll
        for (int kt = 0; kt < 4; ++kt)
            #pragma unroll
            for (int pp = 0; pp < 2; ++pp)
                #pragma unroll
                for (int nt = 0; nt < 4; ++nt)
                    C[nt] = __builtin_amdgcn_mfma_f32_16x16x32_bf16(
                        af[kt], bf[nt][kt][pp], C[nt], 0, 0, 0);

        // lane: local times 2*quad, 2*quad+1; col = w*64 + nt*16 + m
        int row0 = m0 + r * 8 + 2 * quad;
        #pragma unroll
        for (int nt = 0; nt < 4; ++nt) {
            float z0 = C[nt].x + C[nt].y + bb[nt];
            float z1 = C[nt].z + C[nt].w + bb[nt];
            int col = w * 64 + nt * 16 + m;
            outp[(size_t)row0 * U4 + col]       = z0;
            outp[(size_t)(row0 + 1) * U4 + col] = z1;
        }
    }
}

// ---------------- wavefront-batched LSTM recurrence (v9, unchanged) ------
struct Cell {
    const float* xw;
    const unsigned short* rf;
    float* hs;
    float* cs;
    float* hout;
    int init;
    int pad_;
};
struct StageArgs { Cell c[3]; };

__global__ __launch_bounds__(512, 2)
void lstm_rec(StageArgs sa, int Tc)
{
    const Cell ce = sa.c[blockIdx.y];
    const float* __restrict__ xw = ce.xw;
    const unsigned short* __restrict__ Rf = ce.rf;
    float* __restrict__ h_state = ce.hs;
    float* __restrict__ c_state = ce.cs;
    float* __restrict__ h_out = ce.hout;
    const int init = ce.init;

    const int tid  = threadIdx.x;
    const int blk  = blockIdx.x;
    const int lane = tid & 63;
    const int w    = tid >> 6;       // 0..7, units [w*16, w*16+16)
    const int m    = lane & 15;
    const int quad = lane >> 4;

    // [parity][row 0..15][unit] ; row 2s=hi(seq s), 2s+1=lo(seq s)
    __shared__ __align__(16) unsigned short htab[2][16][136];

    // B fragments: [gate][kt][pass] = 32 short8 = 128 regs (v5 layout)
    short8 bf[4][4][2];
    #pragma unroll
    for (int g = 0; g < 4; ++g)
        #pragma unroll
        for (int kt = 0; kt < 4; ++kt)
            #pragma unroll
            for (int pp = 0; pp < 2; ++pp)
                bf[g][kt][pp] = *(const short8*)(
                    Rf + ((size_t)((((w * 4 + g) * 4 + kt) * 2) + pp) * 64 + lane) * 8);

    const int unit = w * 16 + m;
    const int s0   = 2 * quad;       // lane's first local seq
    const int s1   = s0 + 1;

    float c0 = 0.f, c1 = 0.f;
    if (!init) {
        c0 = c_state[(blk * SEQS + s0) * UNITS + unit];
        c1 = c_state[(blk * SEQS + s1) * UNITS + unit];
    }
    // htab init: thread covers seq (tid>>7) and (tid>>7)+4, unit tid&127
    {
        int uu = tid & 127;
        #pragma unroll
        for (int i = 0; i < 2; ++i) {
            int s = (tid >> 7) + i * 4;
            float hv = init ? 0.f : h_state[(blk * SEQS + s) * UNITS + uu];
            unsigned short hi = f2bf(hv);
            htab[0][2 * s][uu]     = hi;
            htab[0][2 * s + 1][uu] = f2bf(hv - bf2f(hi));
        }
    }
    __syncthreads();

    // per-lane xw bases for its two seqs (gate g at +g*128)
    const float* xw0 = xw + (size_t)(blk * SEQS + s0) * Tc * U4 + unit;
    const float* xw1 = xw + (size_t)(blk * SEQS + s1) * Tc * U4 + unit;

    float xa[8], xb[8];   // xa: even steps, xb: odd steps
    #pragma unroll
    for (int g = 0; g < 4; ++g) {
        xa[g]     = xw0[g * UNITS];
        xa[4 + g] = xw1[g * UNITS];
    }
    {
        const size_t o1 = (size_t)((Tc > 1) ? 1 : 0) * U4;
        #pragma unroll
        for (int g = 0; g < 4; ++g) {
            xb[g]     = xw0[o1 + g * UNITS];
            xb[4 + g] = xw1[o1 + g * UNITS];
        }
    }

    float hl0 = 0.f, hl1 = 0.f;

    auto STEP = [&](int t, int p, float (&xc)[8]) {
        short8 af[4];
        #pragma unroll
        for (int kt = 0; kt < 4; ++kt)
            af[kt] = *(const short8*)(&htab[p][m][kt * 32 + quad * 8]);

        f32x4 C0 = {xc[0], 0.f, xc[4], 0.f};
        f32x4 C1 = {xc[1], 0.f, xc[5], 0.f};
        f32x4 C2 = {xc[2], 0.f, xc[6], 0.f};
        f32x4 C3 = {xc[3], 0.f, xc[7], 0.f};

        int tp = t + 2; if (tp >= Tc) tp = Tc - 1;
        const size_t off = (size_t)tp * U4;
        #pragma unroll
        for (int g = 0; g < 4; ++g) {
            xc[g]     = xw0[off + g * UNITS];
            xc[4 + g] = xw1[off + g * UNITS];
        }

        __builtin_amdgcn_s_setprio(1);
        #pragma unroll
        for (int kt = 0; kt < 4; ++kt) {
            #pragma unroll
            for (int pp = 0; pp < 2; ++pp) {
                MFMA_BF16(C0, af[kt], bf[0][kt][pp]);
                MFMA_BF16(C1, af[kt], bf[1][kt][pp]);
                MFMA_BF16(C2, af[kt], bf[2][kt][pp]);
                MFMA_BF16(C3, af[kt], bf[3][kt][pp]);
            }
        }
        __builtin_amdgcn_s_setprio(0);

        float zi0 = C0.x + C0.y, zi1 = C0.z + C0.w;
        float zf0 = C1.x + C1.y, zf1 = C1.z + C1.w;
        float zg0 = C2.x + C2.y, zg1 = C2.z + C2.w;
        float zo0 = C3.x + C3.y, zo1 = C3.z + C3.w;

        float iv0 = sigm(zi0), fv0 = sigm(zf0);
        float gv0 = tanh_fast(zg0), ov0 = sigm(zo0);
        c0 = __builtin_fmaf(fv0, c0, iv0 * gv0);
        float hv0 = ov0 * tanh_fast(c0);

        float iv1 = sigm(zi1), fv1 = sigm(zf1);
        float gv1 = tanh_fast(zg1), ov1 = sigm(zo1);
        c1 = __builtin_fmaf(fv1, c1, iv1 * gv1);
        float hv1 = ov1 * tanh_fast(c1);

        hl0 = hv0; hl1 = hv1;

        unsigned short hi0 = f2bf(hv0);
        htab[p ^ 1][4 * quad + 0][unit] = hi0;
        htab[p ^ 1][4 * quad + 1][unit] = f2bf(hv0 - bf2f(hi0));
        unsigned short hi1 = f2bf(hv1);
        htab[p ^ 1][4 * quad + 2][unit] = hi1;
        htab[p ^ 1][4 * quad + 3][unit] = f2bf(hv1 - bf2f(hi1));

        if (h_out) {
            h_out[((size_t)(blk * SEQS + s0) * Tc + t) * UNITS + unit] = hv0;
            h_out[((size_t)(blk * SEQS + s1) * Tc + t) * UNITS + unit] = hv1;
        }
        barrier_lds_only();   // htab[p^1] visible; vmcnt NOT drained
    };

    #pragma unroll 1
    for (int t = 0; t < Tc; t += 2) {
        STEP(t,     0, xa);
        STEP(t + 1, 1, xb);
    }

    c_state[(blk * SEQS + s0) * UNITS + unit] = c0;
    c_state[(blk * SEQS + s1) * UNITS + unit] = c1;
    h_state[(blk * SEQS + s0) * UNITS + unit] = hl0;
    h_state[(blk * SEQS + s1) * UNITS + unit] = hl1;
}

// ---------------- dense head ----------------
__global__ __launch_bounds__(256)
void dense_head(const float* __restrict__ h2, const float* __restrict__ Wd,
                const float* __restrict__ bd, float* __restrict__ out)
{
    int b = threadIdx.x;
    float acc[6];
    #pragma unroll
    for (int o = 0; o < 6; ++o) acc[o] = bd[o];
    #pragma unroll 4
    for (int k = 0; k < UNITS; ++k) {
        float hv = h2[b * UNITS + k];
        #pragma unroll
        for (int o = 0; o < 6; ++o)
            acc[o] = __builtin_fmaf(hv, Wd[k * 6 + o], acc[o]);
    }
    #pragma unroll
    for (int o = 0; o < 6; ++o) out[b * 6 + o] = acc[o];
}

extern "C" void kernel_launch(void* const* d_in, const int* in_sizes, int n_in,
                              void* d_out, int out_size, void* d_ws, size_t ws_size,
                              hipStream_t stream)
{
    (void)in_sizes; (void)n_in; (void)out_size;
    const float* x  = (const float*)d_in[0];
    const float* Ws[3] = {(const float*)d_in[1], (const float*)d_in[4], (const float*)d_in[7]};
    const float* Rs[3] = {(const float*)d_in[2], (const float*)d_in[5], (const float*)d_in[8]};
    const float* bs[3] = {(const float*)d_in[3], (const float*)d_in[6], (const float*)d_in[9]};
    const float* Wd = (const float*)d_in[10];
    const float* bd = (const float*)d_in[11];
    float* out = (float*)d_out;

    // ws need: 3x xw + 2x hc (per-layer) + hs/cs + Rf + Wf
    //   = Tc*1,835,008 + 2,359,296 bytes
    int tcShift = 7;
    while (tcShift > 2) {
        size_t need = ((size_t)1 << tcShift) * 1835008u + 2359296u;
        if (need <= ws_size) break;
        --tcShift;
    }
    const int Tc = 1 << tcShift;
    const int nCh = TSEQ / Tc;

    float* xw3 = (float*)d_ws;                                   // 3 x [B][Tc][512]
    float* hc2 = xw3 + 3 * (size_t)BATCH * Tc * U4;              // 2 x [B][Tc][128]
    float* hs  = hc2 + 2 * (size_t)BATCH * Tc * UNITS;           // 3 x [B][128]
    float* cs  = hs + 3 * BATCH * UNITS;                         // 3 x [B][128]
    unsigned short* Rf = (unsigned short*)(cs + 3 * BATCH * UNITS); // 3 x 131072 shorts
    unsigned short* Wf = Rf + 3 * 131072;                        // 3 x 131072 shorts

    const size_t xwStride = (size_t)BATCH * Tc * U4;
    const size_t hcStride = (size_t)BATCH * Tc * UNITS;

    r_frag<<<192, 256, 0, stream>>>(Rs[0], Rs[1], Rs[2], Rf);
    w_frag<<<192, 256, 0, stream>>>(Ws[0], Ws[1], Ws[2], Wf);

    // anti-diagonal wavefront over (chunk c, layer lam), c+lam = s.
    // Stage: ONE batched proj launch, then ONE batched lstm launch.
    for (int s = 0; s <= nCh + 1; ++s) {
        int lo = s - (nCh - 1); if (lo < 0) lo = 0;
        int hi = (s < 2) ? s : 2;
        if (lo > hi) continue;

        PStage ps{};
        StageArgs sa{};
        int n = 0;
        for (int lam = lo; lam <= hi; ++lam) {
            int c = s - lam;
            ps.c[n].in   = (lam == 0) ? x : hc2 + (size_t)(lam - 1) * hcStride;
            ps.c[n].out  = xw3 + (size_t)lam * xwStride;
            ps.c[n].wf   = Wf + (size_t)lam * 131072;
            ps.c[n].bias = bs[lam];
            ps.c[n].sB   = (lam == 0) ? TSEQ * FEAT : Tc * UNITS;
            ps.c[n].sT   = (lam == 0) ? FEAT : UNITS;
            ps.c[n].t0   = (lam == 0) ? c * Tc : 0;
            ps.c[n].K    = (lam == 0) ? FEAT : UNITS;

            sa.c[n].xw   = xw3 + (size_t)lam * xwStride;
            sa.c[n].rf   = Rf + (size_t)lam * 131072;
            sa.c[n].hs   = hs + lam * BATCH * UNITS;
            sa.c[n].cs   = cs + lam * BATCH * UNITS;
            sa.c[n].hout = (lam < 2) ? (hc2 + (size_t)lam * hcStride) : nullptr;
            sa.c[n].init = (c == 0) ? 1 : 0;
            ++n;
        }
        proj_mfma<<<dim3(BATCH * Tc / 64, n), 512, 0, stream>>>(ps, tcShift);
        lstm_rec<<<dim3(NBLK, n), 512, 0, stream>>>(sa, Tc);
    }

    dense_head<<<1, 256, 0, stream>>>(hs + 2 * BATCH * UNITS, Wd, bd, out);
}

// Round 8
// 1304.942 us; speedup vs baseline: 1.9832x; 1.1227x over previous
//
#include <hip/hip_runtime.h>
#include <cstdint>
#include <cstddef>

#define U4    512   // 4*U
#define UNITS 128
#define BATCH 256
#define TSEQ  512
#define FEAT  64
#define SEQS  8                  // sequences per lstm_rec block (fills 16 A-rows)
#define NBLK  (BATCH / SEQS)     // 32 blocks per cell

typedef short short8 __attribute__((ext_vector_type(8)));
typedef float f32x4  __attribute__((ext_vector_type(4)));

// MFMA with B-operand constrained to AGPR ("a"): the 128-reg B-fragment set
// lives in the accumulator file and is read DIRECTLY by the MFMA.
// R6 post-mortem: VGPR_Count=104 < 128 B-regs proves bf[] was AGPR-resident
// all along; the "v" constraint (v7) and the builtin (v6) both force B into
// VGPRs -> 128 v_accvgpr_read copies per wave per step (~500cy/SIMD, the
// VALUBusy inflation). ISA 10: A/B may come from VGPR OR AGPR.
#define MFMA_BF16(C, A, B) \
    asm("v_mfma_f32_16x16x32_bf16 %0, %1, %2, %0" : "+v"(C) : "v"(A), "a"(B))

// Raw barrier draining ONLY LDS (v8).
__device__ __forceinline__ void barrier_lds_only() {
    __builtin_amdgcn_sched_barrier(0);
    asm volatile("s_waitcnt lgkmcnt(0)" ::: "memory");
    __builtin_amdgcn_s_barrier();
    __builtin_amdgcn_sched_barrier(0);
}

// ---------------- fast activations (fp32, ~1e-7 rel err) ----------------
__device__ __forceinline__ float sigm(float x) {
    float e = __expf(-x);
    return __fdividef(1.0f, 1.0f + e);
}
__device__ __forceinline__ float tanh_fast(float x) {
    float e = __expf(2.0f * x);
    return 1.0f - __fdividef(2.0f, e + 1.0f);
}

// ---------------- bf16 split helpers (RNE) ----------------
__device__ __forceinline__ unsigned short f2bf(float f) {
    unsigned u = __float_as_uint(f);
    unsigned r = u + 0x7FFFu + ((u >> 16) & 1u);
    return (unsigned short)(r >> 16);
}
__device__ __forceinline__ float bf2f(unsigned short h) {
    return __uint_as_float(((unsigned)h) << 16);
}

// ---------------- R -> bf16 hi/lo MFMA B-fragments (v5 layout, unchanged) -
// Rf[layer][w(8)][gate(4)][kt(4)][pass(2)][lane(64)][8 shorts].
__global__ __launch_bounds__(256)
void r_frag(const float* __restrict__ R0, const float* __restrict__ R1,
            const float* __restrict__ R2, unsigned short* __restrict__ out)
{
    int gid = blockIdx.x * 256 + threadIdx.x;    // 3 * 16384
    int l    = gid >> 14;
    int r    = gid & 16383;
    int lane = r & 63;
    int fi   = r >> 6;            // 0..255
    int pass = fi & 1;
    int kt   = (fi >> 1) & 3;
    int gate = (fi >> 3) & 3;
    int w    = fi >> 5;           // 0..7
    const float* R = (l == 0) ? R0 : (l == 1) ? R1 : R2;

    int col = gate * UNITS + w * 16 + (lane & 15);   // original R column
    int k0  = kt * 32 + (lane >> 4) * 8;
    short8 v;
    #pragma unroll
    for (int j = 0; j < 8; ++j) {
        float x = R[(size_t)(k0 + j) * U4 + col];
        unsigned short hi = f2bf(x);
        unsigned short s = pass ? f2bf(x - bf2f(hi)) : hi;
        v[j] = (short)s;
    }
    *(short8*)(out + (size_t)gid * 8) = v;
}

// ---------------- W -> bf16 hi/lo MFMA B-fragments (v10, r_frag mirror) ---
// Wf[layer][nt(32)][kt(4)][pass(2)][lane(64)][8 shorts]. Layer 0 K=64:
// kt>=2 -> 0.
__global__ __launch_bounds__(256)
void w_frag(const float* __restrict__ W0, const float* __restrict__ W1,
            const float* __restrict__ W2, unsigned short* __restrict__ out)
{
    int gid = blockIdx.x * 256 + threadIdx.x;    // 3 * 16384
    int l    = gid >> 14;
    int r    = gid & 16383;
    int lane = r & 63;
    int fi   = r >> 6;            // 0..255
    int pass = fi & 1;
    int kt   = (fi >> 1) & 3;
    int nt   = fi >> 3;           // 0..31
    const float* W = (l == 0) ? W0 : (l == 1) ? W1 : W2;
    const int K = (l == 0) ? FEAT : UNITS;

    int col = nt * 16 + (lane & 15);
    int k0  = kt * 32 + (lane >> 4) * 8;
    short8 v;
    #pragma unroll
    for (int j = 0; j < 8; ++j) {
        float x = (k0 + j < K) ? W[(size_t)(k0 + j) * U4 + col] : 0.f;
        unsigned short hi = f2bf(x);
        unsigned short s = pass ? f2bf(x - bf2f(hi)) : hi;
        v[j] = (short)s;
    }
    *(short8*)(out + (size_t)gid * 8) = v;
}

// ---------------- projection GEMM via MFMA (v10 + AGPR-B) ----------------
struct PCell {
    const float* in;
    float* out;
    const unsigned short* wf;
    const float* bias;
    int sB, sT, t0, K;
};
struct PStage { PCell c[3]; };

__global__ __launch_bounds__(512, 2)
void proj_mfma(PStage ps, int tcShift)
{
    const PCell ce = ps.c[blockIdx.y];
    const int tid  = threadIdx.x;
    const int lane = tid & 63;
    const int w    = tid >> 6;       // 0..7
    const int m    = lane & 15;
    const int quad = lane >> 4;
    const int TcMask = (1 << tcShift) - 1;
    const int m0 = blockIdx.x * 64;

    // [rowgroup 0..7][16 rows: 2*(t&7)=hi, +1=lo][k], stride 136 like htab
    __shared__ __align__(16) unsigned short atab[8][16][136];

    // B fragments: [nt 0..3][kt 0..3][pass] = 32 short8 -> AGPR-resident
    short8 bf[4][4][2];
    #pragma unroll
    for (int nt = 0; nt < 4; ++nt)
        #pragma unroll
        for (int kt = 0; kt < 4; ++kt)
            #pragma unroll
            for (int pp = 0; pp < 2; ++pp)
                bf[nt][kt][pp] = *(const short8*)(
                    ce.wf + ((size_t)((((w * 4 + nt) * 4 + kt) * 2) + pp) * 64 + lane) * 8);

    // stage 64 rows x 128 k (zeros for k >= K), split hi/lo
    const float* __restrict__ inp = ce.in;
    #pragma unroll
    for (int rep = 0; rep < 16; ++rep) {
        int idx = rep * 512 + tid;
        int row = idx >> 7;          // 0..63
        int k   = idx & 127;
        int rg  = m0 + row;
        int b = rg >> tcShift, tc = rg & TcMask;
        float x = 0.f;
        if (k < ce.K)
            x = inp[(size_t)b * ce.sB + (size_t)(ce.t0 + tc) * ce.sT + k];
        unsigned short hi = f2bf(x);
        atab[row >> 3][2 * (row & 7)][k]     = hi;
        atab[row >> 3][2 * (row & 7) + 1][k] = f2bf(x - bf2f(hi));
    }
    __syncthreads();

    float bb[4];
    #pragma unroll
    for (int nt = 0; nt < 4; ++nt) bb[nt] = ce.bias[w * 64 + nt * 16 + m];

    float* __restrict__ outp = ce.out;
    #pragma unroll 1
    for (int r = 0; r < 8; ++r) {
        short8 af[4];
        #pragma unroll
        for (int kt = 0; kt < 4; ++kt)
            af[kt] = *(const short8*)(&atab[r][m][kt * 32 + quad * 8]);

        f32x4 C[4];
        #pragma unroll
        for (int nt = 0; nt < 4; ++nt) C[nt] = f32x4{0.f, 0.f, 0.f, 0.f};

        #pragma unroll
        for (int kt = 0; kt < 4; ++kt)
            #pragma unroll
            for (int pp = 0; pp < 2; ++pp)
                #pragma unroll
                for (int nt = 0; nt < 4; ++nt)
                    MFMA_BF16(C[nt], af[kt], bf[nt][kt][pp]);

        // lane: local times 2*quad, 2*quad+1; col = w*64 + nt*16 + m
        int row0 = m0 + r * 8 + 2 * quad;
        #pragma unroll
        for (int nt = 0; nt < 4; ++nt) {
            float z0 = C[nt].x + C[nt].y + bb[nt];
            float z1 = C[nt].z + C[nt].w + bb[nt];
            int col = w * 64 + nt * 16 + m;
            outp[(size_t)row0 * U4 + col]       = z0;
            outp[(size_t)(row0 + 1) * U4 + col] = z1;
        }
    }
}

// ---------------- wavefront-batched LSTM recurrence (v11 = v9 + AGPR-B) --
struct Cell {
    const float* xw;
    const unsigned short* rf;
    float* hs;
    float* cs;
    float* hout;
    int init;
    int pad_;
};
struct StageArgs { Cell c[3]; };

__global__ __launch_bounds__(512, 2)
void lstm_rec(StageArgs sa, int Tc)
{
    const Cell ce = sa.c[blockIdx.y];
    const float* __restrict__ xw = ce.xw;
    const unsigned short* __restrict__ Rf = ce.rf;
    float* __restrict__ h_state = ce.hs;
    float* __restrict__ c_state = ce.cs;
    float* __restrict__ h_out = ce.hout;
    const int init = ce.init;

    const int tid  = threadIdx.x;
    const int blk  = blockIdx.x;
    const int lane = tid & 63;
    const int w    = tid >> 6;       // 0..7, units [w*16, w*16+16)
    const int m    = lane & 15;
    const int quad = lane >> 4;

    // [parity][row 0..15][unit] ; row 2s=hi(seq s), 2s+1=lo(seq s)
    __shared__ __align__(16) unsigned short htab[2][16][136];

    // B fragments: [gate][kt][pass] = 32 short8 -> AGPR-resident, read
    // directly by the MFMA (no accvgpr copies).
    short8 bf[4][4][2];
    #pragma unroll
    for (int g = 0; g < 4; ++g)
        #pragma unroll
        for (int kt = 0; kt < 4; ++kt)
            #pragma unroll
            for (int pp = 0; pp < 2; ++pp)
                bf[g][kt][pp] = *(const short8*)(
                    Rf + ((size_t)((((w * 4 + g) * 4 + kt) * 2) + pp) * 64 + lane) * 8);

    const int unit = w * 16 + m;
    const int s0   = 2 * quad;       // lane's first local seq
    const int s1   = s0 + 1;

    float c0 = 0.f, c1 = 0.f;
    if (!init) {
        c0 = c_state[(blk * SEQS + s0) * UNITS + unit];
        c1 = c_state[(blk * SEQS + s1) * UNITS + unit];
    }
    // htab init: thread covers seq (tid>>7) and (tid>>7)+4, unit tid&127
    {
        int uu = tid & 127;
        #pragma unroll
        for (int i = 0; i < 2; ++i) {
            int s = (tid >> 7) + i * 4;
            float hv = init ? 0.f : h_state[(blk * SEQS + s) * UNITS + uu];
            unsigned short hi = f2bf(hv);
            htab[0][2 * s][uu]     = hi;
            htab[0][2 * s + 1][uu] = f2bf(hv - bf2f(hi));
        }
    }
    __syncthreads();

    // per-lane xw bases for its two seqs (gate g at +g*128)
    const float* xw0 = xw + (size_t)(blk * SEQS + s0) * Tc * U4 + unit;
    const float* xw1 = xw + (size_t)(blk * SEQS + s1) * Tc * U4 + unit;

    float xa[8], xb[8];   // xa: even steps, xb: odd steps
    #pragma unroll
    for (int g = 0; g < 4; ++g) {
        xa[g]     = xw0[g * UNITS];
        xa[4 + g] = xw1[g * UNITS];
    }
    {
        const size_t o1 = (size_t)((Tc > 1) ? 1 : 0) * U4;
        #pragma unroll
        for (int g = 0; g < 4; ++g) {
            xb[g]     = xw0[o1 + g * UNITS];
            xb[4 + g] = xw1[o1 + g * UNITS];
        }
    }

    float hl0 = 0.f, hl1 = 0.f;

    auto STEP = [&](int t, int p, float (&xc)[8]) {
        short8 af[4];
        #pragma unroll
        for (int kt = 0; kt < 4; ++kt)
            af[kt] = *(const short8*)(&htab[p][m][kt * 32 + quad * 8]);

        f32x4 C0 = {xc[0], 0.f, xc[4], 0.f};
        f32x4 C1 = {xc[1], 0.f, xc[5], 0.f};
        f32x4 C2 = {xc[2], 0.f, xc[6], 0.f};
        f32x4 C3 = {xc[3], 0.f, xc[7], 0.f};

        int tp = t + 2; if (tp >= Tc) tp = Tc - 1;
        const size_t off = (size_t)tp * U4;
        #pragma unroll
        for (int g = 0; g < 4; ++g) {
            xc[g]     = xw0[off + g * UNITS];
            xc[4 + g] = xw1[off + g * UNITS];
        }

        __builtin_amdgcn_s_setprio(1);
        #pragma unroll
        for (int kt = 0; kt < 4; ++kt) {
            #pragma unroll
            for (int pp = 0; pp < 2; ++pp) {
                MFMA_BF16(C0, af[kt], bf[0][kt][pp]);
                MFMA_BF16(C1, af[kt], bf[1][kt][pp]);
                MFMA_BF16(C2, af[kt], bf[2][kt][pp]);
                MFMA_BF16(C3, af[kt], bf[3][kt][pp]);
            }
        }
        __builtin_amdgcn_s_setprio(0);

        float zi0 = C0.x + C0.y, zi1 = C0.z + C0.w;
        float zf0 = C1.x + C1.y, zf1 = C1.z + C1.w;
        float zg0 = C2.x + C2.y, zg1 = C2.z + C2.w;
        float zo0 = C3.x + C3.y, zo1 = C3.z + C3.w;

        float iv0 = sigm(zi0), fv0 = sigm(zf0);
        float gv0 = tanh_fast(zg0), ov0 = sigm(zo0);
        c0 = __builtin_fmaf(fv0, c0, iv0 * gv0);
        float hv0 = ov0 * tanh_fast(c0);

        float iv1 = sigm(zi1), fv1 = sigm(zf1);
        float gv1 = tanh_fast(zg1), ov1 = sigm(zo1);
        c1 = __builtin_fmaf(fv1, c1, iv1 * gv1);
        float hv1 = ov1 * tanh_fast(c1);

        hl0 = hv0; hl1 = hv1;

        unsigned short hi0 = f2bf(hv0);
        htab[p ^ 1][4 * quad + 0][unit] = hi0;
        htab[p ^ 1][4 * quad + 1][unit] = f2bf(hv0 - bf2f(hi0));
        unsigned short hi1 = f2bf(hv1);
        htab[p ^ 1][4 * quad + 2][unit] = hi1;
        htab[p ^ 1][4 * quad + 3][unit] = f2bf(hv1 - bf2f(hi1));

        if (h_out) {
            h_out[((size_t)(blk * SEQS + s0) * Tc + t) * UNITS + unit] = hv0;
            h_out[((size_t)(blk * SEQS + s1) * Tc + t) * UNITS + unit] = hv1;
        }
        barrier_lds_only();   // htab[p^1] visible; vmcnt NOT drained
    };

    #pragma unroll 1
    for (int t = 0; t < Tc; t += 2) {
        STEP(t,     0, xa);
        STEP(t + 1, 1, xb);
    }

    c_state[(blk * SEQS + s0) * UNITS + unit] = c0;
    c_state[(blk * SEQS + s1) * UNITS + unit] = c1;
    h_state[(blk * SEQS + s0) * UNITS + unit] = hl0;
    h_state[(blk * SEQS + s1) * UNITS + unit] = hl1;
}

// ---------------- dense head ----------------
__global__ __launch_bounds__(256)
void dense_head(const float* __restrict__ h2, const float* __restrict__ Wd,
                const float* __restrict__ bd, float* __restrict__ out)
{
    int b = threadIdx.x;
    float acc[6];
    #pragma unroll
    for (int o = 0; o < 6; ++o) acc[o] = bd[o];
    #pragma unroll 4
    for (int k = 0; k < UNITS; ++k) {
        float hv = h2[b * UNITS + k];
        #pragma unroll
        for (int o = 0; o < 6; ++o)
            acc[o] = __builtin_fmaf(hv, Wd[k * 6 + o], acc[o]);
    }
    #pragma unroll
    for (int o = 0; o < 6; ++o) out[b * 6 + o] = acc[o];
}

extern "C" void kernel_launch(void* const* d_in, const int* in_sizes, int n_in,
                              void* d_out, int out_size, void* d_ws, size_t ws_size,
                              hipStream_t stream)
{
    (void)in_sizes; (void)n_in; (void)out_size;
    const float* x  = (const float*)d_in[0];
    const float* Ws[3] = {(const float*)d_in[1], (const float*)d_in[4], (const float*)d_in[7]};
    const float* Rs[3] = {(const float*)d_in[2], (const float*)d_in[5], (const float*)d_in[8]};
    const float* bs[3] = {(const float*)d_in[3], (const float*)d_in[6], (const float*)d_in[9]};
    const float* Wd = (const float*)d_in[10];
    const float* bd = (const float*)d_in[11];
    float* out = (float*)d_out;

    // Tc=64 (nCh=8): pipeline fill/drain waste (1 + 2/nCh) drops 1.5x->1.25x
    // (R6: lstm wall = TSEQ*step*(1+2/nCh); step time is nCh-invariant).
    // ws need: 3x xw + 2x hc (per-layer) + hs/cs + Rf + Wf
    int tcShift = 6;
    while (tcShift > 2) {
        size_t need = ((size_t)1 << tcShift) * 1835008u + 2359296u;
        if (need <= ws_size) break;
        --tcShift;
    }
    const int Tc = 1 << tcShift;
    const int nCh = TSEQ / Tc;

    float* xw3 = (float*)d_ws;                                   // 3 x [B][Tc][512]
    float* hc2 = xw3 + 3 * (size_t)BATCH * Tc * U4;              // 2 x [B][Tc][128]
    float* hs  = hc2 + 2 * (size_t)BATCH * Tc * UNITS;           // 3 x [B][128]
    float* cs  = hs + 3 * BATCH * UNITS;                         // 3 x [B][128]
    unsigned short* Rf = (unsigned short*)(cs + 3 * BATCH * UNITS); // 3 x 131072 shorts
    unsigned short* Wf = Rf + 3 * 131072;                        // 3 x 131072 shorts

    const size_t xwStride = (size_t)BATCH * Tc * U4;
    const size_t hcStride = (size_t)BATCH * Tc * UNITS;

    r_frag<<<192, 256, 0, stream>>>(Rs[0], Rs[1], Rs[2], Rf);
    w_frag<<<192, 256, 0, stream>>>(Ws[0], Ws[1], Ws[2], Wf);

    // anti-diagonal wavefront over (chunk c, layer lam), c+lam = s.
    for (int s = 0; s <= nCh + 1; ++s) {
        int lo = s - (nCh - 1); if (lo < 0) lo = 0;
        int hi = (s < 2) ? s : 2;
        if (lo > hi) continue;

        PStage ps{};
        StageArgs sa{};
        int n = 0;
        for (int lam = lo; lam <= hi; ++lam) {
            int c = s - lam;
            ps.c[n].in   = (lam == 0) ? x : hc2 + (size_t)(lam - 1) * hcStride;
            ps.c[n].out  = xw3 + (size_t)lam * xwStride;
            ps.c[n].wf   = Wf + (size_t)lam * 131072;
            ps.c[n].bias = bs[lam];
            ps.c[n].sB   = (lam == 0) ? TSEQ * FEAT : Tc * UNITS;
            ps.c[n].sT   = (lam == 0) ? FEAT : UNITS;
            ps.c[n].t0   = (lam == 0) ? c * Tc : 0;
            ps.c[n].K    = (lam == 0) ? FEAT : UNITS;

            sa.c[n].xw   = xw3 + (size_t)lam * xwStride;
            sa.c[n].rf   = Rf + (size_t)lam * 131072;
            sa.c[n].hs   = hs + lam * BATCH * UNITS;
            sa.c[n].cs   = cs + lam * BATCH * UNITS;
            sa.c[n].hout = (lam < 2) ? (hc2 + (size_t)lam * hcStride) : nullptr;
            sa.c[n].init = (c == 0) ? 1 : 0;
            ++n;
        }
        proj_mfma<<<dim3(BATCH * Tc / 64, n), 512, 0, stream>>>(ps, tcShift);
        lstm_rec<<<dim3(NBLK, n), 512, 0, stream>>>(sa, Tc);
    }

    dense_head<<<1, 256, 0, stream>>>(hs + 2 * BATCH * UNITS, Wd, bd, out);
}

// Round 9
// 1265.828 us; speedup vs baseline: 2.0445x; 1.0309x over previous
//
#include <hip/hip_runtime.h>
#include <cstdint>
#include <cstddef>

#define U4    512   // 4*U
#define UNITS 128
#define BATCH 256
#define TSEQ  512
#define FEAT  64
#define SEQS  8                  // sequences per lstm_rec block (fills 16 A-rows)
#define NBLK  (BATCH / SEQS)     // 32 blocks per cell

typedef short short8 __attribute__((ext_vector_type(8)));
typedef float f32x4  __attribute__((ext_vector_type(4)));

// MFMA inline asm ("a" on B keeps the AGPR-resident fragment set readable
// in place; perf-equivalent to builtin per R7/R8 but pins allocation).
#define MFMA_BF16(C, A, B) \
    asm("v_mfma_f32_16x16x32_bf16 %0, %1, %2, %0" : "+v"(C) : "v"(A), "a"(B))

// Raw barrier draining ONLY LDS (v8).
__device__ __forceinline__ void barrier_lds_only() {
    __builtin_amdgcn_sched_barrier(0);
    asm volatile("s_waitcnt lgkmcnt(0)" ::: "memory");
    __builtin_amdgcn_s_barrier();
    __builtin_amdgcn_sched_barrier(0);
}

// ---------------- fast activations (fp32, ~1e-7 rel err) ----------------
__device__ __forceinline__ float sigm(float x) {
    float e = __expf(-x);
    return __fdividef(1.0f, 1.0f + e);
}
__device__ __forceinline__ float tanh_fast(float x) {
    float e = __expf(2.0f * x);
    return 1.0f - __fdividef(2.0f, e + 1.0f);
}

// ---------------- bf16 split helpers (RNE) ----------------
__device__ __forceinline__ unsigned short f2bf(float f) {
    unsigned u = __float_as_uint(f);
    unsigned r = u + 0x7FFFu + ((u >> 16) & 1u);
    return (unsigned short)(r >> 16);
}
__device__ __forceinline__ float bf2f(unsigned short h) {
    return __uint_as_float(((unsigned)h) << 16);
}

// ---------------- R & W -> bf16 hi/lo MFMA B-fragments (fused launch) -----
// blocks 0-191: Rf (v5 gate-interleaved layout)
//   Rf[layer][w(8)][gate(4)][kt(4)][pass(2)][lane(64)][8 shorts]
// blocks 192-383: Wf (proj layout, no permute)
//   Wf[layer][nt(32)][kt(4)][pass(2)][lane(64)][8 shorts]; layer0 K=64 pad 0
__global__ __launch_bounds__(256)
void rw_frag(const float* __restrict__ R0, const float* __restrict__ R1,
             const float* __restrict__ R2,
             const float* __restrict__ W0, const float* __restrict__ W1,
             const float* __restrict__ W2,
             unsigned short* __restrict__ Rf, unsigned short* __restrict__ Wf)
{
    if (blockIdx.x < 192) {
        int gid = blockIdx.x * 256 + threadIdx.x;    // 3 * 16384
        int l    = gid >> 14;
        int r    = gid & 16383;
        int lane = r & 63;
        int fi   = r >> 6;            // 0..255
        int pass = fi & 1;
        int kt   = (fi >> 1) & 3;
        int gate = (fi >> 3) & 3;
        int w    = fi >> 5;           // 0..7
        const float* R = (l == 0) ? R0 : (l == 1) ? R1 : R2;

        int col = gate * UNITS + w * 16 + (lane & 15);   // original R column
        int k0  = kt * 32 + (lane >> 4) * 8;
        short8 v;
        #pragma unroll
        for (int j = 0; j < 8; ++j) {
            float x = R[(size_t)(k0 + j) * U4 + col];
            unsigned short hi = f2bf(x);
            unsigned short s = pass ? f2bf(x - bf2f(hi)) : hi;
            v[j] = (short)s;
        }
        *(short8*)(Rf + (size_t)gid * 8) = v;
    } else {
        int gid = (blockIdx.x - 192) * 256 + threadIdx.x;
        int l    = gid >> 14;
        int r    = gid & 16383;
        int lane = r & 63;
        int fi   = r >> 6;            // 0..255
        int pass = fi & 1;
        int kt   = (fi >> 1) & 3;
        int nt   = fi >> 3;           // 0..31
        const float* W = (l == 0) ? W0 : (l == 1) ? W1 : W2;
        const int K = (l == 0) ? FEAT : UNITS;

        int col = nt * 16 + (lane & 15);
        int k0  = kt * 32 + (lane >> 4) * 8;
        short8 v;
        #pragma unroll
        for (int j = 0; j < 8; ++j) {
            float x = (k0 + j < K) ? W[(size_t)(k0 + j) * U4 + col] : 0.f;
            unsigned short hi = f2bf(x);
            unsigned short s = pass ? f2bf(x - bf2f(hi)) : hi;
            v[j] = (short)s;
        }
        *(short8*)(Wf + (size_t)gid * 8) = v;
    }
}

// ---------------- projection GEMM via MFMA (v10, unchanged) --------------
struct PCell {
    const float* in;
    float* out;
    const unsigned short* wf;
    const float* bias;
    int sB, sT, t0, K;
};
struct PStage { PCell c[3]; };

__global__ __launch_bounds__(512, 2)
void proj_mfma(PStage ps, int tcShift)
{
    const PCell ce = ps.c[blockIdx.y];
    const int tid  = threadIdx.x;
    const int lane = tid & 63;
    const int w    = tid >> 6;       // 0..7
    const int m    = lane & 15;
    const int quad = lane >> 4;
    const int TcMask = (1 << tcShift) - 1;
    const int m0 = blockIdx.x * 64;

    __shared__ __align__(16) unsigned short atab[8][16][136];

    short8 bf[4][4][2];
    #pragma unroll
    for (int nt = 0; nt < 4; ++nt)
        #pragma unroll
        for (int kt = 0; kt < 4; ++kt)
            #pragma unroll
            for (int pp = 0; pp < 2; ++pp)
                bf[nt][kt][pp] = *(const short8*)(
                    ce.wf + ((size_t)((((w * 4 + nt) * 4 + kt) * 2) + pp) * 64 + lane) * 8);

    const float* __restrict__ inp = ce.in;
    #pragma unroll
    for (int rep = 0; rep < 16; ++rep) {
        int idx = rep * 512 + tid;
        int row = idx >> 7;          // 0..63
        int k   = idx & 127;
        int rg  = m0 + row;
        int b = rg >> tcShift, tc = rg & TcMask;
        float x = 0.f;
        if (k < ce.K)
            x = inp[(size_t)b * ce.sB + (size_t)(ce.t0 + tc) * ce.sT + k];
        unsigned short hi = f2bf(x);
        atab[row >> 3][2 * (row & 7)][k]     = hi;
        atab[row >> 3][2 * (row & 7) + 1][k] = f2bf(x - bf2f(hi));
    }
    __syncthreads();

    float bb[4];
    #pragma unroll
    for (int nt = 0; nt < 4; ++nt) bb[nt] = ce.bias[w * 64 + nt * 16 + m];

    float* __restrict__ outp = ce.out;
    #pragma unroll 1
    for (int r = 0; r < 8; ++r) {
        short8 af[4];
        #pragma unroll
        for (int kt = 0; kt < 4; ++kt)
            af[kt] = *(const short8*)(&atab[r][m][kt * 32 + quad * 8]);

        f32x4 C[4];
        #pragma unroll
        for (int nt = 0; nt < 4; ++nt) C[nt] = f32x4{0.f, 0.f, 0.f, 0.f};

        #pragma unroll
        for (int kt = 0; kt < 4; ++kt)
            #pragma unroll
            for (int pp = 0; pp < 2; ++pp)
                #pragma unroll
                for (int nt = 0; nt < 4; ++nt)
                    MFMA_BF16(C[nt], af[kt], bf[nt][kt][pp]);

        int row0 = m0 + r * 8 + 2 * quad;
        #pragma unroll
        for (int nt = 0; nt < 4; ++nt) {
            float z0 = C[nt].x + C[nt].y + bb[nt];
            float z1 = C[nt].z + C[nt].w + bb[nt];
            int col = w * 64 + nt * 16 + m;
            outp[(size_t)row0 * U4 + col]       = z0;
            outp[(size_t)(row0 + 1) * U4 + col] = z1;
        }
    }
}

// ---------------- wavefront-batched LSTM recurrence (v12) ----------------
// v12 change: STEP split into two MFMA groups with the i/f activations
// placed between them. Group1 = i,f chains (16 MFMAs); their sigmoids
// depend only on group1 and can dual-issue under group2's (g,o) ~620cy of
// MFMA-pipe time instead of serializing after all 32 MFMAs (R8 model:
// 2 phase-locked waves/SIMD -> MFMA phase and VALU phase serialize).
struct Cell {
    const float* xw;
    const unsigned short* rf;
    float* hs;
    float* cs;
    float* hout;
    int init;
    int pad_;
};
struct StageArgs { Cell c[3]; };

__global__ __launch_bounds__(512, 2)
void lstm_rec(StageArgs sa, int Tc)
{
    const Cell ce = sa.c[blockIdx.y];
    const float* __restrict__ xw = ce.xw;
    const unsigned short* __restrict__ Rf = ce.rf;
    float* __restrict__ h_state = ce.hs;
    float* __restrict__ c_state = ce.cs;
    float* __restrict__ h_out = ce.hout;
    const int init = ce.init;

    const int tid  = threadIdx.x;
    const int blk  = blockIdx.x;
    const int lane = tid & 63;
    const int w    = tid >> 6;       // 0..7, units [w*16, w*16+16)
    const int m    = lane & 15;
    const int quad = lane >> 4;

    // [parity][row 0..15][unit] ; row 2s=hi(seq s), 2s+1=lo(seq s)
    __shared__ __align__(16) unsigned short htab[2][16][136];

    // B fragments: [gate][kt][pass] = 32 short8, AGPR-resident
    short8 bf[4][4][2];
    #pragma unroll
    for (int g = 0; g < 4; ++g)
        #pragma unroll
        for (int kt = 0; kt < 4; ++kt)
            #pragma unroll
            for (int pp = 0; pp < 2; ++pp)
                bf[g][kt][pp] = *(const short8*)(
                    Rf + ((size_t)((((w * 4 + g) * 4 + kt) * 2) + pp) * 64 + lane) * 8);

    const int unit = w * 16 + m;
    const int s0   = 2 * quad;       // lane's first local seq
    const int s1   = s0 + 1;

    float c0 = 0.f, c1 = 0.f;
    if (!init) {
        c0 = c_state[(blk * SEQS + s0) * UNITS + unit];
        c1 = c_state[(blk * SEQS + s1) * UNITS + unit];
    }
    // htab init: thread covers seq (tid>>7) and (tid>>7)+4, unit tid&127
    {
        int uu = tid & 127;
        #pragma unroll
        for (int i = 0; i < 2; ++i) {
            int s = (tid >> 7) + i * 4;
            float hv = init ? 0.f : h_state[(blk * SEQS + s) * UNITS + uu];
            unsigned short hi = f2bf(hv);
            htab[0][2 * s][uu]     = hi;
            htab[0][2 * s + 1][uu] = f2bf(hv - bf2f(hi));
        }
    }
    __syncthreads();

    // per-lane xw bases for its two seqs (gate g at +g*128)
    const float* xw0 = xw + (size_t)(blk * SEQS + s0) * Tc * U4 + unit;
    const float* xw1 = xw + (size_t)(blk * SEQS + s1) * Tc * U4 + unit;

    float xa[8], xb[8];   // xa: even steps, xb: odd steps
    #pragma unroll
    for (int g = 0; g < 4; ++g) {
        xa[g]     = xw0[g * UNITS];
        xa[4 + g] = xw1[g * UNITS];
    }
    {
        const size_t o1 = (size_t)((Tc > 1) ? 1 : 0) * U4;
        #pragma unroll
        for (int g = 0; g < 4; ++g) {
            xb[g]     = xw0[o1 + g * UNITS];
            xb[4 + g] = xw1[o1 + g * UNITS];
        }
    }

    float hl0 = 0.f, hl1 = 0.f;

    auto STEP = [&](int t, int p, float (&xc)[8]) {
        short8 af[4];
        #pragma unroll
        for (int kt = 0; kt < 4; ++kt)
            af[kt] = *(const short8*)(&htab[p][m][kt * 32 + quad * 8]);

        // C init folds xw into hi-row slots (regs 0,2); lo rows 0
        f32x4 C0 = {xc[0], 0.f, xc[4], 0.f};
        f32x4 C1 = {xc[1], 0.f, xc[5], 0.f};
        f32x4 C2 = {xc[2], 0.f, xc[6], 0.f};
        f32x4 C3 = {xc[3], 0.f, xc[7], 0.f};

        // prefetch t+2 into xc; stays in flight across the lds-only barrier
        int tp = t + 2; if (tp >= Tc) tp = Tc - 1;
        const size_t off = (size_t)tp * U4;
        #pragma unroll
        for (int g = 0; g < 4; ++g) {
            xc[g]     = xw0[off + g * UNITS];
            xc[4 + g] = xw1[off + g * UNITS];
        }

        __builtin_amdgcn_s_setprio(1);
        // ---- MFMA group 1: i (C0) and f (C1) chains ----
        #pragma unroll
        for (int kt = 0; kt < 4; ++kt) {
            #pragma unroll
            for (int pp = 0; pp < 2; ++pp) {
                MFMA_BF16(C0, af[kt], bf[0][kt][pp]);
                MFMA_BF16(C1, af[kt], bf[1][kt][pp]);
            }
        }

        // ---- early i/f activations (overlap with group 2 MFMA time) ----
        float zi0 = C0.x + C0.y, zi1 = C0.z + C0.w;
        float zf0 = C1.x + C1.y, zf1 = C1.z + C1.w;
        float iv0 = sigm(zi0), iv1 = sigm(zi1);
        float fv0 = sigm(zf0), fv1 = sigm(zf1);

        // ---- MFMA group 2: g (C2) and o (C3) chains ----
        #pragma unroll
        for (int kt = 0; kt < 4; ++kt) {
            #pragma unroll
            for (int pp = 0; pp < 2; ++pp) {
                MFMA_BF16(C2, af[kt], bf[2][kt][pp]);
                MFMA_BF16(C3, af[kt], bf[3][kt][pp]);
            }
        }
        __builtin_amdgcn_s_setprio(0);

        // ---- remaining phase B ----
        float zg0 = C2.x + C2.y, zg1 = C2.z + C2.w;
        float zo0 = C3.x + C3.y, zo1 = C3.z + C3.w;

        float gv0 = tanh_fast(zg0), ov0 = sigm(zo0);
        c0 = __builtin_fmaf(fv0, c0, iv0 * gv0);
        float hv0 = ov0 * tanh_fast(c0);

        float gv1 = tanh_fast(zg1), ov1 = sigm(zo1);
        c1 = __builtin_fmaf(fv1, c1, iv1 * gv1);
        float hv1 = ov1 * tanh_fast(c1);

        hl0 = hv0; hl1 = hv1;

        unsigned short hi0 = f2bf(hv0);
        htab[p ^ 1][4 * quad + 0][unit] = hi0;
        htab[p ^ 1][4 * quad + 1][unit] = f2bf(hv0 - bf2f(hi0));
        unsigned short hi1 = f2bf(hv1);
        htab[p ^ 1][4 * quad + 2][unit] = hi1;
        htab[p ^ 1][4 * quad + 3][unit] = f2bf(hv1 - bf2f(hi1));

        if (h_out) {
            h_out[((size_t)(blk * SEQS + s0) * Tc + t) * UNITS + unit] = hv0;
            h_out[((size_t)(blk * SEQS + s1) * Tc + t) * UNITS + unit] = hv1;
        }
        barrier_lds_only();   // htab[p^1] visible; vmcnt NOT drained
    };

    #pragma unroll 1
    for (int t = 0; t < Tc; t += 2) {
        STEP(t,     0, xa);
        STEP(t + 1, 1, xb);
    }

    c_state[(blk * SEQS + s0) * UNITS + unit] = c0;
    c_state[(blk * SEQS + s1) * UNITS + unit] = c1;
    h_state[(blk * SEQS + s0) * UNITS + unit] = hl0;
    h_state[(blk * SEQS + s1) * UNITS + unit] = hl1;
}

// ---------------- dense head ----------------
__global__ __launch_bounds__(256)
void dense_head(const float* __restrict__ h2, const float* __restrict__ Wd,
                const float* __restrict__ bd, float* __restrict__ out)
{
    int b = threadIdx.x;
    float acc[6];
    #pragma unroll
    for (int o = 0; o < 6; ++o) acc[o] = bd[o];
    #pragma unroll 4
    for (int k = 0; k < UNITS; ++k) {
        float hv = h2[b * UNITS + k];
        #pragma unroll
        for (int o = 0; o < 6; ++o)
            acc[o] = __builtin_fmaf(hv, Wd[k * 6 + o], acc[o]);
    }
    #pragma unroll
    for (int o = 0; o < 6; ++o) out[b * 6 + o] = acc[o];
}

extern "C" void kernel_launch(void* const* d_in, const int* in_sizes, int n_in,
                              void* d_out, int out_size, void* d_ws, size_t ws_size,
                              hipStream_t stream)
{
    (void)in_sizes; (void)n_in; (void)out_size;
    const float* x  = (const float*)d_in[0];
    const float* Ws[3] = {(const float*)d_in[1], (const float*)d_in[4], (const float*)d_in[7]};
    const float* Rs[3] = {(const float*)d_in[2], (const float*)d_in[5], (const float*)d_in[8]};
    const float* bs[3] = {(const float*)d_in[3], (const float*)d_in[6], (const float*)d_in[9]};
    const float* Wd = (const float*)d_in[10];
    const float* bd = (const float*)d_in[11];
    float* out = (float*)d_out;

    // Tc=64 (nCh=8): pipeline fill/drain waste 1.25x (validated R8).
    int tcShift = 6;
    while (tcShift > 2) {
        size_t need = ((size_t)1 << tcShift) * 1835008u + 2359296u;
        if (need <= ws_size) break;
        --tcShift;
    }
    const int Tc = 1 << tcShift;
    const int nCh = TSEQ / Tc;

    float* xw3 = (float*)d_ws;                                   // 3 x [B][Tc][512]
    float* hc2 = xw3 + 3 * (size_t)BATCH * Tc * U4;              // 2 x [B][Tc][128]
    float* hs  = hc2 + 2 * (size_t)BATCH * Tc * UNITS;           // 3 x [B][128]
    float* cs  = hs + 3 * BATCH * UNITS;                         // 3 x [B][128]
    unsigned short* Rf = (unsigned short*)(cs + 3 * BATCH * UNITS); // 3 x 131072 shorts
    unsigned short* Wf = Rf + 3 * 131072;                        // 3 x 131072 shorts

    const size_t xwStride = (size_t)BATCH * Tc * U4;
    const size_t hcStride = (size_t)BATCH * Tc * UNITS;

    rw_frag<<<384, 256, 0, stream>>>(Rs[0], Rs[1], Rs[2], Ws[0], Ws[1], Ws[2], Rf, Wf);

    // anti-diagonal wavefront over (chunk c, layer lam), c+lam = s.
    for (int s = 0; s <= nCh + 1; ++s) {
        int lo = s - (nCh - 1); if (lo < 0) lo = 0;
        int hi = (s < 2) ? s : 2;
        if (lo > hi) continue;

        PStage ps{};
        StageArgs sa{};
        int n = 0;
        for (int lam = lo; lam <= hi; ++lam) {
            int c = s - lam;
            ps.c[n].in   = (lam == 0) ? x : hc2 + (size_t)(lam - 1) * hcStride;
            ps.c[n].out  = xw3 + (size_t)lam * xwStride;
            ps.c[n].wf   = Wf + (size_t)lam * 131072;
            ps.c[n].bias = bs[lam];
            ps.c[n].sB   = (lam == 0) ? TSEQ * FEAT : Tc * UNITS;
            ps.c[n].sT   = (lam == 0) ? FEAT : UNITS;
            ps.c[n].t0   = (lam == 0) ? c * Tc : 0;
            ps.c[n].K    = (lam == 0) ? FEAT : UNITS;

            sa.c[n].xw   = xw3 + (size_t)lam * xwStride;
            sa.c[n].rf   = Rf + (size_t)lam * 131072;
            sa.c[n].hs   = hs + lam * BATCH * UNITS;
            sa.c[n].cs   = cs + lam * BATCH * UNITS;
            sa.c[n].hout = (lam < 2) ? (hc2 + (size_t)lam * hcStride) : nullptr;
            sa.c[n].init = (c == 0) ? 1 : 0;
            ++n;
        }
        proj_mfma<<<dim3(BATCH * Tc / 64, n), 512, 0, stream>>>(ps, tcShift);
        lstm_rec<<<dim3(NBLK, n), 512, 0, stream>>>(sa, Tc);
    }

    dense_head<<<1, 256, 0, stream>>>(hs + 2 * BATCH * UNITS, Wd, bd, out);
}

// Round 10
// 1112.659 us; speedup vs baseline: 2.3259x; 1.1377x over previous
//
#include <hip/hip_runtime.h>
#include <cstdint>
#include <cstddef>

#define U4    512   // 4*U
#define UNITS 128
#define BATCH 256
#define TSEQ  512
#define FEAT  64
#define SEQS  8                  // sequences per lstm cell block (fills 16 A-rows)
#define NBLK  (BATCH / SEQS)     // 32 blocks per lstm cell

typedef short short8 __attribute__((ext_vector_type(8)));
typedef float f32x4  __attribute__((ext_vector_type(4)));
typedef unsigned short tab_t[16][136];

// MFMA inline asm ("a" on B keeps the AGPR-resident fragment set readable
// in place; perf-equivalent to builtin per R7/R8 but pins allocation).
#define MFMA_BF16(C, A, B) \
    asm("v_mfma_f32_16x16x32_bf16 %0, %1, %2, %0" : "+v"(C) : "v"(A), "a"(B))

// Raw barrier draining ONLY LDS (v8).
__device__ __forceinline__ void barrier_lds_only() {
    __builtin_amdgcn_sched_barrier(0);
    asm volatile("s_waitcnt lgkmcnt(0)" ::: "memory");
    __builtin_amdgcn_s_barrier();
    __builtin_amdgcn_sched_barrier(0);
}

// ---------------- fast activations (fp32, ~1e-7 rel err) ----------------
__device__ __forceinline__ float sigm(float x) {
    float e = __expf(-x);
    return __fdividef(1.0f, 1.0f + e);
}
__device__ __forceinline__ float tanh_fast(float x) {
    float e = __expf(2.0f * x);
    return 1.0f - __fdividef(2.0f, e + 1.0f);
}

// ---------------- bf16 split helpers (RNE) ----------------
__device__ __forceinline__ unsigned short f2bf(float f) {
    unsigned u = __float_as_uint(f);
    unsigned r = u + 0x7FFFu + ((u >> 16) & 1u);
    return (unsigned short)(r >> 16);
}
__device__ __forceinline__ float bf2f(unsigned short h) {
    return __uint_as_float(((unsigned)h) << 16);
}

// ---------------- R & W -> bf16 hi/lo MFMA B-fragments (fused launch) -----
__global__ __launch_bounds__(256)
void rw_frag(const float* __restrict__ R0, const float* __restrict__ R1,
             const float* __restrict__ R2,
             const float* __restrict__ W0, const float* __restrict__ W1,
             const float* __restrict__ W2,
             unsigned short* __restrict__ Rf, unsigned short* __restrict__ Wf)
{
    if (blockIdx.x < 192) {
        int gid = blockIdx.x * 256 + threadIdx.x;    // 3 * 16384
        int l    = gid >> 14;
        int r    = gid & 16383;
        int lane = r & 63;
        int fi   = r >> 6;
        int pass = fi & 1;
        int kt   = (fi >> 1) & 3;
        int gate = (fi >> 3) & 3;
        int w    = fi >> 5;
        const float* R = (l == 0) ? R0 : (l == 1) ? R1 : R2;

        int col = gate * UNITS + w * 16 + (lane & 15);
        int k0  = kt * 32 + (lane >> 4) * 8;
        short8 v;
        #pragma unroll
        for (int j = 0; j < 8; ++j) {
            float x = R[(size_t)(k0 + j) * U4 + col];
            unsigned short hi = f2bf(x);
            unsigned short s = pass ? f2bf(x - bf2f(hi)) : hi;
            v[j] = (short)s;
        }
        *(short8*)(Rf + (size_t)gid * 8) = v;
    } else {
        int gid = (blockIdx.x - 192) * 256 + threadIdx.x;
        int l    = gid >> 14;
        int r    = gid & 16383;
        int lane = r & 63;
        int fi   = r >> 6;
        int pass = fi & 1;
        int kt   = (fi >> 1) & 3;
        int nt   = fi >> 3;
        const float* W = (l == 0) ? W0 : (l == 1) ? W1 : W2;
        const int K = (l == 0) ? FEAT : UNITS;

        int col = nt * 16 + (lane & 15);
        int k0  = kt * 32 + (lane >> 4) * 8;
        short8 v;
        #pragma unroll
        for (int j = 0; j < 8; ++j) {
            float x = (k0 + j < K) ? W[(size_t)(k0 + j) * U4 + col] : 0.f;
            unsigned short hi = f2bf(x);
            unsigned short s = pass ? f2bf(x - bf2f(hi)) : hi;
            v[j] = (short)s;
        }
        *(short8*)(Wf + (size_t)gid * 8) = v;
    }
}

// ---------------- projection cell (device body, v13) ---------------------
// packed=1: input is u32 (h_hi | h_lo<<16) from lstm -> direct unpack,
// no RNE split. packed=0: fp32 input (layer 0 / x), split here.
struct PCell {
    const void* in;
    float* out;
    const unsigned short* wf;
    const float* bias;
    int sB, sT, t0, K, packed, pad_;
};
struct PStage { PCell c[2]; };

__device__ __forceinline__ void proj_body(const PCell& ce, int bx, int tcShift,
                                          tab_t* __restrict__ atab)
{
    const int tid  = threadIdx.x;
    const int lane = tid & 63;
    const int w    = tid >> 6;
    const int m    = lane & 15;
    const int quad = lane >> 4;
    const int TcMask = (1 << tcShift) - 1;
    const int m0 = bx * 64;

    short8 bf[4][4][2];
    #pragma unroll
    for (int nt = 0; nt < 4; ++nt)
        #pragma unroll
        for (int kt = 0; kt < 4; ++kt)
            #pragma unroll
            for (int pp = 0; pp < 2; ++pp)
                bf[nt][kt][pp] = *(const short8*)(
                    ce.wf + ((size_t)((((w * 4 + nt) * 4 + kt) * 2) + pp) * 64 + lane) * 8);

    if (ce.packed) {
        const unsigned int* __restrict__ inp = (const unsigned int*)ce.in;
        #pragma unroll
        for (int rep = 0; rep < 16; ++rep) {
            int idx = rep * 512 + tid;
            int row = idx >> 7;
            int k   = idx & 127;
            int rg  = m0 + row;
            int b = rg >> tcShift, tc = rg & TcMask;
            unsigned int u = inp[(size_t)b * ce.sB + (size_t)(ce.t0 + tc) * ce.sT + k];
            atab[row >> 3][2 * (row & 7)][k]     = (unsigned short)(u & 0xFFFFu);
            atab[row >> 3][2 * (row & 7) + 1][k] = (unsigned short)(u >> 16);
        }
    } else {
        const float* __restrict__ inp = (const float*)ce.in;
        #pragma unroll
        for (int rep = 0; rep < 16; ++rep) {
            int idx = rep * 512 + tid;
            int row = idx >> 7;
            int k   = idx & 127;
            int rg  = m0 + row;
            int b = rg >> tcShift, tc = rg & TcMask;
            float x = 0.f;
            if (k < ce.K)
                x = inp[(size_t)b * ce.sB + (size_t)(ce.t0 + tc) * ce.sT + k];
            unsigned short hi = f2bf(x);
            atab[row >> 3][2 * (row & 7)][k]     = hi;
            atab[row >> 3][2 * (row & 7) + 1][k] = f2bf(x - bf2f(hi));
        }
    }
    __syncthreads();

    float bb[4];
    #pragma unroll
    for (int nt = 0; nt < 4; ++nt) bb[nt] = ce.bias[w * 64 + nt * 16 + m];

    float* __restrict__ outp = ce.out;
    #pragma unroll 1
    for (int r = 0; r < 8; ++r) {
        short8 af[4];
        #pragma unroll
        for (int kt = 0; kt < 4; ++kt)
            af[kt] = *(const short8*)(&atab[r][m][kt * 32 + quad * 8]);

        f32x4 C[4];
        #pragma unroll
        for (int nt = 0; nt < 4; ++nt) C[nt] = f32x4{0.f, 0.f, 0.f, 0.f};

        #pragma unroll
        for (int kt = 0; kt < 4; ++kt)
            #pragma unroll
            for (int pp = 0; pp < 2; ++pp)
                #pragma unroll
                for (int nt = 0; nt < 4; ++nt)
                    MFMA_BF16(C[nt], af[kt], bf[nt][kt][pp]);

        int row0 = m0 + r * 8 + 2 * quad;
        #pragma unroll
        for (int nt = 0; nt < 4; ++nt) {
            float z0 = C[nt].x + C[nt].y + bb[nt];
            float z1 = C[nt].z + C[nt].w + bb[nt];
            int col = w * 64 + nt * 16 + m;
            outp[(size_t)row0 * U4 + col]       = z0;
            outp[(size_t)(row0 + 1) * U4 + col] = z1;
        }
    }
}

__global__ __launch_bounds__(512, 2)
void proj_mfma(PStage ps, int tcShift)
{
    __shared__ __align__(16) unsigned short smem[8 * 16 * 136];
    proj_body(ps.c[blockIdx.y], blockIdx.x, tcShift, (tab_t*)smem);
}

// ---------------- LSTM recurrence cell (device body, v12 math) -----------
struct Cell {
    const float* xw;
    const unsigned short* rf;
    float* hs;
    float* cs;
    unsigned int* hout;    // packed h_hi | h_lo<<16 (v13)
    int init;
    int pad_;
};

__device__ __forceinline__ void lstm_body(const Cell& ce, int blk, int Tc,
                                          tab_t* __restrict__ htab)
{
    const float* __restrict__ xw = ce.xw;
    const unsigned short* __restrict__ Rf = ce.rf;
    float* __restrict__ h_state = ce.hs;
    float* __restrict__ c_state = ce.cs;
    unsigned int* __restrict__ h_out = ce.hout;
    const int init = ce.init;

    const int tid  = threadIdx.x;
    const int lane = tid & 63;
    const int w    = tid >> 6;
    const int m    = lane & 15;
    const int quad = lane >> 4;

    short8 bf[4][4][2];
    #pragma unroll
    for (int g = 0; g < 4; ++g)
        #pragma unroll
        for (int kt = 0; kt < 4; ++kt)
            #pragma unroll
            for (int pp = 0; pp < 2; ++pp)
                bf[g][kt][pp] = *(const short8*)(
                    Rf + ((size_t)((((w * 4 + g) * 4 + kt) * 2) + pp) * 64 + lane) * 8);

    const int unit = w * 16 + m;
    const int s0   = 2 * quad;
    const int s1   = s0 + 1;

    float c0 = 0.f, c1 = 0.f;
    if (!init) {
        c0 = c_state[(blk * SEQS + s0) * UNITS + unit];
        c1 = c_state[(blk * SEQS + s1) * UNITS + unit];
    }
    {
        int uu = tid & 127;
        #pragma unroll
        for (int i = 0; i < 2; ++i) {
            int s = (tid >> 7) + i * 4;
            float hv = init ? 0.f : h_state[(blk * SEQS + s) * UNITS + uu];
            unsigned short hi = f2bf(hv);
            htab[0][2 * s][uu]     = hi;
            htab[0][2 * s + 1][uu] = f2bf(hv - bf2f(hi));
        }
    }
    __syncthreads();

    const float* xw0 = xw + (size_t)(blk * SEQS + s0) * Tc * U4 + unit;
    const float* xw1 = xw + (size_t)(blk * SEQS + s1) * Tc * U4 + unit;

    float xa[8], xb[8];
    #pragma unroll
    for (int g = 0; g < 4; ++g) {
        xa[g]     = xw0[g * UNITS];
        xa[4 + g] = xw1[g * UNITS];
    }
    {
        const size_t o1 = (size_t)((Tc > 1) ? 1 : 0) * U4;
        #pragma unroll
        for (int g = 0; g < 4; ++g) {
            xb[g]     = xw0[o1 + g * UNITS];
            xb[4 + g] = xw1[o1 + g * UNITS];
        }
    }

    float hl0 = 0.f, hl1 = 0.f;

    auto STEP = [&](int t, int p, float (&xc)[8]) {
        short8 af[4];
        #pragma unroll
        for (int kt = 0; kt < 4; ++kt)
            af[kt] = *(const short8*)(&htab[p][m][kt * 32 + quad * 8]);

        f32x4 C0 = {xc[0], 0.f, xc[4], 0.f};
        f32x4 C1 = {xc[1], 0.f, xc[5], 0.f};
        f32x4 C2 = {xc[2], 0.f, xc[6], 0.f};
        f32x4 C3 = {xc[3], 0.f, xc[7], 0.f};

        int tp = t + 2; if (tp >= Tc) tp = Tc - 1;
        const size_t off = (size_t)tp * U4;
        #pragma unroll
        for (int g = 0; g < 4; ++g) {
            xc[g]     = xw0[off + g * UNITS];
            xc[4 + g] = xw1[off + g * UNITS];
        }

        __builtin_amdgcn_s_setprio(1);
        #pragma unroll
        for (int kt = 0; kt < 4; ++kt) {
            #pragma unroll
            for (int pp = 0; pp < 2; ++pp) {
                MFMA_BF16(C0, af[kt], bf[0][kt][pp]);
                MFMA_BF16(C1, af[kt], bf[1][kt][pp]);
            }
        }
        float zi0 = C0.x + C0.y, zi1 = C0.z + C0.w;
        float zf0 = C1.x + C1.y, zf1 = C1.z + C1.w;
        float iv0 = sigm(zi0), iv1 = sigm(zi1);
        float fv0 = sigm(zf0), fv1 = sigm(zf1);

        #pragma unroll
        for (int kt = 0; kt < 4; ++kt) {
            #pragma unroll
            for (int pp = 0; pp < 2; ++pp) {
                MFMA_BF16(C2, af[kt], bf[2][kt][pp]);
                MFMA_BF16(C3, af[kt], bf[3][kt][pp]);
            }
        }
        __builtin_amdgcn_s_setprio(0);

        float zg0 = C2.x + C2.y, zg1 = C2.z + C2.w;
        float zo0 = C3.x + C3.y, zo1 = C3.z + C3.w;

        float gv0 = tanh_fast(zg0), ov0 = sigm(zo0);
        c0 = __builtin_fmaf(fv0, c0, iv0 * gv0);
        float hv0 = ov0 * tanh_fast(c0);

        float gv1 = tanh_fast(zg1), ov1 = sigm(zo1);
        c1 = __builtin_fmaf(fv1, c1, iv1 * gv1);
        float hv1 = ov1 * tanh_fast(c1);

        hl0 = hv0; hl1 = hv1;

        unsigned short hi0 = f2bf(hv0);
        unsigned short lo0 = f2bf(hv0 - bf2f(hi0));
        htab[p ^ 1][4 * quad + 0][unit] = hi0;
        htab[p ^ 1][4 * quad + 1][unit] = lo0;
        unsigned short hi1 = f2bf(hv1);
        unsigned short lo1 = f2bf(hv1 - bf2f(hi1));
        htab[p ^ 1][4 * quad + 2][unit] = hi1;
        htab[p ^ 1][4 * quad + 3][unit] = lo1;

        if (h_out) {
            h_out[((size_t)(blk * SEQS + s0) * Tc + t) * UNITS + unit] =
                (unsigned int)hi0 | ((unsigned int)lo0 << 16);
            h_out[((size_t)(blk * SEQS + s1) * Tc + t) * UNITS + unit] =
                (unsigned int)hi1 | ((unsigned int)lo1 << 16);
        }
        barrier_lds_only();
    };

    #pragma unroll 1
    for (int t = 0; t < Tc; t += 2) {
        STEP(t,     0, xa);
        STEP(t + 1, 1, xb);
    }

    c_state[(blk * SEQS + s0) * UNITS + unit] = c0;
    c_state[(blk * SEQS + s1) * UNITS + unit] = c1;
    h_state[(blk * SEQS + s0) * UNITS + unit] = hl0;
    h_state[(blk * SEQS + s1) * UNITS + unit] = hl1;
}

// ---------------- fused stage: lstm cells + hidden layer-0 proj ----------
// v13: layer-0 proj (chunk s+1) has no lstm dependency -> its 256 blocks
// ride in the SAME launch as the stage's lstm cells (<=96 CUs, 1 block/CU
// register-bound) and fill the ~160 idle CUs. xw0 double-buffered by chunk
// parity (writer c+1 / reader c disjoint; prior-parity reader finished 2
// stages ago).
struct FusedArgs {
    Cell lc[3];
    PCell pc;
    int n_lstm;
    int has_proj;
};

__global__ __launch_bounds__(512, 2)
void stage_fused(FusedArgs fa, int Tc, int tcShift)
{
    __shared__ __align__(16) unsigned short smem[8 * 16 * 136];
    int bx = blockIdx.x;
    if (bx < fa.n_lstm * NBLK)
        lstm_body(fa.lc[bx >> 5], bx & 31, Tc, (tab_t*)smem);
    else
        proj_body(fa.pc, bx - fa.n_lstm * NBLK, tcShift, (tab_t*)smem);
}

// ---------------- dense head ----------------
__global__ __launch_bounds__(256)
void dense_head(const float* __restrict__ h2, const float* __restrict__ Wd,
                const float* __restrict__ bd, float* __restrict__ out)
{
    int b = threadIdx.x;
    float acc[6];
    #pragma unroll
    for (int o = 0; o < 6; ++o) acc[o] = bd[o];
    #pragma unroll 4
    for (int k = 0; k < UNITS; ++k) {
        float hv = h2[b * UNITS + k];
        #pragma unroll
        for (int o = 0; o < 6; ++o)
            acc[o] = __builtin_fmaf(hv, Wd[k * 6 + o], acc[o]);
    }
    #pragma unroll
    for (int o = 0; o < 6; ++o) out[b * 6 + o] = acc[o];
}

extern "C" void kernel_launch(void* const* d_in, const int* in_sizes, int n_in,
                              void* d_out, int out_size, void* d_ws, size_t ws_size,
                              hipStream_t stream)
{
    (void)in_sizes; (void)n_in; (void)out_size;
    const float* x  = (const float*)d_in[0];
    const float* Ws[3] = {(const float*)d_in[1], (const float*)d_in[4], (const float*)d_in[7]};
    const float* Rs[3] = {(const float*)d_in[2], (const float*)d_in[5], (const float*)d_in[8]};
    const float* bs[3] = {(const float*)d_in[3], (const float*)d_in[6], (const float*)d_in[9]};
    const float* Wd = (const float*)d_in[10];
    const float* bd = (const float*)d_in[11];
    float* out = (float*)d_out;

    // ws: 4 xw buffers (xw0 x2 parity, xw1, xw2) + 2 hc (packed u32) +
    // hs/cs + Rf + Wf.  per-Tc bytes = 4*524288 + 2*131072 = 2359296.
    int tcShift = 6;
    while (tcShift > 2) {
        size_t need = ((size_t)1 << tcShift) * 2359296u + 2359296u;
        if (need <= ws_size) break;
        --tcShift;
    }
    const int Tc = 1 << tcShift;
    const int nCh = TSEQ / Tc;
    const int projGrid = BATCH * Tc / 64;

    const size_t xwStride = (size_t)BATCH * Tc * U4;
    const size_t hcStride = (size_t)BATCH * Tc * UNITS;

    float* xw = (float*)d_ws;                                    // 4 x xwStride
    unsigned int* hc = (unsigned int*)(xw + 4 * xwStride);       // 2 x hcStride
    float* hs = (float*)(hc + 2 * hcStride);                     // 3 x [B][128]
    float* cs = hs + 3 * BATCH * UNITS;
    unsigned short* Rf = (unsigned short*)(cs + 3 * BATCH * UNITS); // 3 x 131072
    unsigned short* Wf = Rf + 3 * 131072;                        // 3 x 131072

    rw_frag<<<384, 256, 0, stream>>>(Rs[0], Rs[1], Rs[2], Ws[0], Ws[1], Ws[2], Rf, Wf);

    // prologue: layer-0 proj of chunk 0 into xw[parity 0]
    {
        PStage ps{};
        ps.c[0].in = x; ps.c[0].out = xw; ps.c[0].wf = Wf; ps.c[0].bias = bs[0];
        ps.c[0].sB = TSEQ * FEAT; ps.c[0].sT = FEAT; ps.c[0].t0 = 0;
        ps.c[0].K = FEAT; ps.c[0].packed = 0;
        proj_mfma<<<dim3(projGrid, 1), 512, 0, stream>>>(ps, tcShift);
    }

    // anti-diagonal wavefront over (chunk c, layer lam), c + lam = s.
    for (int s = 0; s <= nCh + 1; ++s) {
        int lo = s - (nCh - 1); if (lo < 0) lo = 0;
        int hi = (s < 2) ? s : 2;
        if (lo > hi) continue;

        // layers 1-2 proj (depends on hc written last stage)
        PStage ps{};
        int pn = 0;
        int plo = (lo > 1) ? lo : 1;
        for (int lam = plo; lam <= hi; ++lam) {
            ps.c[pn].in   = hc + (size_t)(lam - 1) * hcStride;
            ps.c[pn].out  = xw + (size_t)(1 + lam) * xwStride;   // lam1->slot2, lam2->slot3
            ps.c[pn].wf   = Wf + (size_t)lam * 131072;
            ps.c[pn].bias = bs[lam];
            ps.c[pn].sB   = Tc * UNITS;
            ps.c[pn].sT   = UNITS;
            ps.c[pn].t0   = 0;
            ps.c[pn].K    = UNITS;
            ps.c[pn].packed = 1;
            ++pn;
        }
        if (pn) proj_mfma<<<dim3(projGrid, pn), 512, 0, stream>>>(ps, tcShift);

        // fused: lstm cells + hidden layer-0 proj for chunk s+1
        FusedArgs fa{};
        int n = 0;
        for (int lam = lo; lam <= hi; ++lam) {
            int c = s - lam;
            fa.lc[n].xw   = (lam == 0) ? xw + (size_t)(c & 1) * xwStride
                                       : xw + (size_t)(1 + lam) * xwStride;
            fa.lc[n].rf   = Rf + (size_t)lam * 131072;
            fa.lc[n].hs   = hs + lam * BATCH * UNITS;
            fa.lc[n].cs   = cs + lam * BATCH * UNITS;
            fa.lc[n].hout = (lam < 2) ? (hc + (size_t)lam * hcStride) : nullptr;
            fa.lc[n].init = (c == 0) ? 1 : 0;
            ++n;
        }
        fa.n_lstm = n;
        int c0 = s + 1;
        fa.has_proj = (c0 <= nCh - 1) ? 1 : 0;
        if (fa.has_proj) {
            fa.pc.in = x; fa.pc.out = xw + (size_t)(c0 & 1) * xwStride;
            fa.pc.wf = Wf; fa.pc.bias = bs[0];
            fa.pc.sB = TSEQ * FEAT; fa.pc.sT = FEAT; fa.pc.t0 = c0 * Tc;
            fa.pc.K = FEAT; fa.pc.packed = 0;
        }
        int gridx = n * NBLK + (fa.has_proj ? projGrid : 0);
        stage_fused<<<dim3(gridx), 512, 0, stream>>>(fa, Tc, tcShift);
    }

    dense_head<<<1, 256, 0, stream>>>(hs + 2 * BATCH * UNITS, Wd, bd, out);
}